// Round 1
// baseline (443.547 us; speedup 1.0000x reference)
//
#include <hip/hip_runtime.h>
#include <math.h>

#define N_NODES 10000
#define E_IN    320000
#define E_TOT   330000   /* E_IN + N self loops */
#define H1      4
#define C       128
#define F1      512      /* H1*C */

// ---------------- layer-1 feature + per-node attention halves ----------------
// h1[n,j] = x[n,0]*W1[0,j] + x[n,1]*W1[1,j];  as1[n,h] = sum_c h1*att_src
__global__ __launch_bounds__(512) void k_h1(
    const float* __restrict__ x, const float* __restrict__ W1,
    const float* __restrict__ asw, const float* __restrict__ adw,
    float* __restrict__ h1, float* __restrict__ as1, float* __restrict__ ad1)
{
    int n = blockIdx.x, j = threadIdx.x;
    float x0 = x[2*n], x1 = x[2*n+1];
    float v = x0 * W1[j] + x1 * W1[F1 + j];
    h1[n*F1 + j] = v;
    float ps = v * asw[j];
    float pd = v * adw[j];
    #pragma unroll
    for (int d = 32; d > 0; d >>= 1) { ps += __shfl_down(ps, d); pd += __shfl_down(pd, d); }
    __shared__ float sp[8], dp[8];
    int wave = j >> 6, lane = j & 63;
    if (lane == 0) { sp[wave] = ps; dp[wave] = pd; }
    __syncthreads();
    if (j < H1) {
        as1[n*H1 + j] = sp[2*j] + sp[2*j+1];
        ad1[n*H1 + j] = dp[2*j] + dp[2*j+1];
    }
}

// ---------------- CSR build: histogram -> scan -> scatter ----------------
__global__ void k_zero_int(int* __restrict__ p, int n) {
    int i = blockIdx.x * blockDim.x + threadIdx.x;
    if (i < n) p[i] = 0;
}

__global__ void k_hist(const int* __restrict__ dsti, int* __restrict__ deg) {
    int t = blockIdx.x * blockDim.x + threadIdx.x;
    if (t >= E_TOT) return;
    int d = (t < E_IN) ? dsti[t] : (t - E_IN);
    atomicAdd(&deg[d], 1);
}

__global__ __launch_bounds__(256) void k_scan(
    const int* __restrict__ deg, int* __restrict__ offs, int* __restrict__ cursor)
{
    __shared__ int part[256];
    int tid = threadIdx.x;
    const int CH = (N_NODES + 255) / 256;   // 40
    int start = tid * CH;
    int sum = 0;
    for (int i = 0; i < CH; ++i) { int idx = start + i; if (idx < N_NODES) sum += deg[idx]; }
    part[tid] = sum;
    __syncthreads();
    for (int off = 1; off < 256; off <<= 1) {
        int v = (tid >= off) ? part[tid - off] : 0;
        __syncthreads();
        part[tid] += v;
        __syncthreads();
    }
    int base = (tid == 0) ? 0 : part[tid - 1];
    for (int i = 0; i < CH; ++i) {
        int idx = start + i;
        if (idx < N_NODES) { offs[idx] = base; cursor[idx] = base; base += deg[idx]; }
    }
    if (tid == 255) offs[N_NODES] = base;   // == E_TOT
}

__global__ void k_scatter(const int* __restrict__ dsti, int* __restrict__ cursor,
                          int* __restrict__ perm) {
    int t = blockIdx.x * blockDim.x + threadIdx.x;
    if (t >= E_TOT) return;
    int d = (t < E_IN) ? dsti[t] : (t - E_IN);
    int pos = atomicAdd(&cursor[d], 1);
    perm[pos] = t;
}

// ---------------- layer-1 edge scores ----------------
__global__ void k_scores1(const int* __restrict__ srci, const int* __restrict__ dsti,
                          const float* __restrict__ as1, const float* __restrict__ ad1,
                          float* __restrict__ e1)
{
    int t = blockIdx.x * blockDim.x + threadIdx.x;
    if (t >= E_TOT) return;
    int s = (t < E_IN) ? srci[t] : (t - E_IN);
    int d = (t < E_IN) ? dsti[t] : (t - E_IN);
    float4 a = *(const float4*)(as1 + 4*s);
    float4 b = *(const float4*)(ad1 + 4*d);
    float4 e;
    e.x = a.x + b.x; e.x = e.x > 0.f ? e.x : 0.2f*e.x;
    e.y = a.y + b.y; e.y = e.y > 0.f ? e.y : 0.2f*e.y;
    e.z = a.z + b.z; e.z = e.z > 0.f ? e.z : 0.2f*e.z;
    e.w = a.w + b.w; e.w = e.w > 0.f ? e.w : 0.2f*e.w;
    *(float4*)(e1 + 4*t) = e;
}

// ---------------- layer-1 segment max + sum (wave per node) ----------------
__global__ __launch_bounds__(256) void k_msum1(
    const int* __restrict__ offs, const int* __restrict__ perm,
    const float* __restrict__ e1, float* __restrict__ m1, float* __restrict__ invs1)
{
    int node = blockIdx.x * 4 + (threadIdx.x >> 6);
    int lane = threadIdx.x & 63;
    if (node >= N_NODES) return;
    int beg = offs[node], end = offs[node + 1];
    int h = lane & 3;
    float mx = -1e30f;
    for (int i = beg + (lane >> 2); i < end; i += 16)
        mx = fmaxf(mx, e1[4*perm[i] + h]);
    #pragma unroll
    for (int d = 4; d < 64; d <<= 1) mx = fmaxf(mx, __shfl_xor(mx, d));
    float s = 0.f;
    for (int i = beg + (lane >> 2); i < end; i += 16)
        s += __expf(e1[4*perm[i] + h] - mx);
    #pragma unroll
    for (int d = 4; d < 64; d <<= 1) s += __shfl_xor(s, d);
    if (lane < 4) { m1[node*4 + lane] = mx; invs1[node*4 + lane] = 1.f / (s + 1e-16f); }
}

// ---------------- layer-1 aggregation + bias + relu ----------------
__global__ __launch_bounds__(256) void k_agg1(
    const int* __restrict__ offs, const int* __restrict__ perm,
    const int* __restrict__ srci, const float* __restrict__ e1,
    const float* __restrict__ m1, const float* __restrict__ invs1,
    const float* __restrict__ h1, const float* __restrict__ b1,
    float* __restrict__ h_act)
{
    int n = blockIdx.x, tid = threadIdx.x;
    int hA = tid >> 7;        // head for channel tid      (0 or 1)
    int hB = hA + 2;          // head for channel 256+tid  (2 or 3)
    float mA = m1[4*n + hA], iA = invs1[4*n + hA];
    float mB = m1[4*n + hB], iB = invs1[4*n + hB];
    int beg = offs[n], end = offs[n + 1];
    float a0 = 0.f, a1 = 0.f;
    for (int i = beg; i < end; ++i) {
        int t = perm[i];
        int s = (t < E_IN) ? srci[t] : (t - E_IN);
        float w0 = __expf(e1[4*t + hA] - mA) * iA;
        float w1 = __expf(e1[4*t + hB] - mB) * iB;
        const float* hr = h1 + s * F1;
        a0 += w0 * hr[tid];
        a1 += w1 * hr[256 + tid];
    }
    float v0 = a0 + b1[tid];        h_act[n*F1 + tid]       = v0 > 0.f ? v0 : 0.f;
    float v1 = a1 + b1[256 + tid];  h_act[n*F1 + 256 + tid] = v1 > 0.f ? v1 : 0.f;
}

// ---------------- layer-2 GEMM: h2 = h_act @ W2  (512 -> 128) ----------------
__global__ __launch_bounds__(128) void k_gemm2(
    const float* __restrict__ h_act, const float* __restrict__ W2,
    float* __restrict__ h2)
{
    __shared__ float tile[16 * F1];            // 32 KiB, 16 node rows
    int n0 = blockIdx.x * 16;
    int tid = threadIdx.x;
    const float* src = h_act + (size_t)n0 * F1;
    for (int idx = tid * 4; idx < 16 * F1; idx += 128 * 4)
        *(float4*)(tile + idx) = *(const float4*)(src + idx);
    __syncthreads();
    float acc[16];
    #pragma unroll
    for (int j = 0; j < 16; ++j) acc[j] = 0.f;
    for (int k = 0; k < F1; ++k) {
        float w = W2[k * C + tid];
        #pragma unroll
        for (int j = 0; j < 16; ++j) acc[j] += tile[j * F1 + k] * w;
    }
    #pragma unroll
    for (int j = 0; j < 16; ++j) h2[(n0 + j) * C + tid] = acc[j];
}

// ---------------- layer-2 per-node attention halves ----------------
__global__ __launch_bounds__(256) void k_attn2(
    const float* __restrict__ h2, const float* __restrict__ asw,
    const float* __restrict__ adw, float* __restrict__ as2, float* __restrict__ ad2)
{
    int node = blockIdx.x * 4 + (threadIdx.x >> 6);
    int lane = threadIdx.x & 63;
    if (node >= N_NODES) return;
    const float* hr = h2 + node * C;
    float v0 = hr[lane], v1 = hr[64 + lane];
    float ps = v0 * asw[lane] + v1 * asw[64 + lane];
    float pd = v0 * adw[lane] + v1 * adw[64 + lane];
    #pragma unroll
    for (int d = 32; d > 0; d >>= 1) { ps += __shfl_down(ps, d); pd += __shfl_down(pd, d); }
    if (lane == 0) { as2[node] = ps; ad2[node] = pd; }
}

__global__ void k_scores2(const int* __restrict__ srci, const int* __restrict__ dsti,
                          const float* __restrict__ as2, const float* __restrict__ ad2,
                          float* __restrict__ e2)
{
    int t = blockIdx.x * blockDim.x + threadIdx.x;
    if (t >= E_TOT) return;
    int s = (t < E_IN) ? srci[t] : (t - E_IN);
    int d = (t < E_IN) ? dsti[t] : (t - E_IN);
    float e = as2[s] + ad2[d];
    e2[t] = e > 0.f ? e : 0.2f * e;
}

__global__ __launch_bounds__(256) void k_msum2(
    const int* __restrict__ offs, const int* __restrict__ perm,
    const float* __restrict__ e2, float* __restrict__ m2, float* __restrict__ invs2)
{
    int node = blockIdx.x * 4 + (threadIdx.x >> 6);
    int lane = threadIdx.x & 63;
    if (node >= N_NODES) return;
    int beg = offs[node], end = offs[node + 1];
    float mx = -1e30f;
    for (int i = beg + lane; i < end; i += 64) mx = fmaxf(mx, e2[perm[i]]);
    #pragma unroll
    for (int d = 32; d > 0; d >>= 1) mx = fmaxf(mx, __shfl_xor(mx, d));
    float s = 0.f;
    for (int i = beg + lane; i < end; i += 64) s += __expf(e2[perm[i]] - mx);
    #pragma unroll
    for (int d = 32; d > 0; d >>= 1) s += __shfl_xor(s, d);
    if (lane == 0) { m2[node] = mx; invs2[node] = 1.f / (s + 1e-16f); }
}

// ---------------- layer-2 aggregation + bias + relu + final projection ----------------
__global__ __launch_bounds__(128) void k_agg2(
    const int* __restrict__ offs, const int* __restrict__ perm,
    const int* __restrict__ srci, const float* __restrict__ e2,
    const float* __restrict__ m2, const float* __restrict__ invs2,
    const float* __restrict__ h2, const float* __restrict__ b2,
    const float* __restrict__ Wp, const float* __restrict__ bp,
    float* __restrict__ out)
{
    int n = blockIdx.x, c = threadIdx.x;
    float m = m2[n], is = invs2[n];
    int beg = offs[n], end = offs[n + 1];
    float acc = 0.f;
    for (int i = beg; i < end; ++i) {
        int t = perm[i];
        int s = (t < E_IN) ? srci[t] : (t - E_IN);
        float w = __expf(e2[t] - m) * is;
        acc += w * h2[s * C + c];
    }
    float v = acc + b2[c];
    v = v > 0.f ? v : 0.f;
    float contrib = v * Wp[c];
    #pragma unroll
    for (int d = 32; d > 0; d >>= 1) contrib += __shfl_down(contrib, d);
    __shared__ float part[2];
    if ((c & 63) == 0) part[c >> 6] = contrib;
    __syncthreads();
    if (c == 0) out[n] = part[0] + part[1] + bp[0];
}

// ---------------- host launcher ----------------
extern "C" void kernel_launch(void* const* d_in, const int* in_sizes, int n_in,
                              void* d_out, int out_size, void* d_ws, size_t ws_size,
                              hipStream_t stream)
{
    const float* x    = (const float*)d_in[0];
    const int*   ei   = (const int*)d_in[1];
    const int*   srci = ei;
    const int*   dsti = ei + E_IN;
    const float* W1   = (const float*)d_in[2];
    const float* as1w = (const float*)d_in[3];
    const float* ad1w = (const float*)d_in[4];
    const float* b1   = (const float*)d_in[5];
    const float* W2   = (const float*)d_in[6];
    const float* as2w = (const float*)d_in[7];
    const float* ad2w = (const float*)d_in[8];
    const float* b2   = (const float*)d_in[9];
    const float* Wp   = (const float*)d_in[10];
    const float* bp   = (const float*)d_in[11];
    float* out = (float*)d_out;

    char* ws = (char*)d_ws;
    size_t off = 0;
    auto alloc = [&](size_t bytes) -> char* {
        char* p = ws + off;
        off = (off + bytes + 255) & ~(size_t)255;
        return p;
    };
    float* h1    = (float*)alloc((size_t)N_NODES * F1 * 4);
    float* h_act = (float*)alloc((size_t)N_NODES * F1 * 4);
    float* h2    = (float*)alloc((size_t)N_NODES * C * 4);
    float* e1    = (float*)alloc((size_t)E_TOT * 4 * 4);
    float* e2    = (float*)alloc((size_t)E_TOT * 4);
    float* as1   = (float*)alloc((size_t)N_NODES * 4 * 4);
    float* ad1   = (float*)alloc((size_t)N_NODES * 4 * 4);
    float* m1    = (float*)alloc((size_t)N_NODES * 4 * 4);
    float* invs1 = (float*)alloc((size_t)N_NODES * 4 * 4);
    float* as2   = (float*)alloc((size_t)N_NODES * 4);
    float* ad2   = (float*)alloc((size_t)N_NODES * 4);
    float* m2    = (float*)alloc((size_t)N_NODES * 4);
    float* invs2 = (float*)alloc((size_t)N_NODES * 4);
    int*   deg    = (int*)alloc((size_t)N_NODES * 4);
    int*   offs   = (int*)alloc((size_t)(N_NODES + 1) * 4);
    int*   cursor = (int*)alloc((size_t)N_NODES * 4);
    int*   perm   = (int*)alloc((size_t)E_TOT * 4);

    const int EB = 256;
    const int egrid = (E_TOT + EB - 1) / EB;

    // layer-1 features + attention halves
    k_h1<<<N_NODES, 512, 0, stream>>>(x, W1, as1w, ad1w, h1, as1, ad1);

    // CSR build (reused by both layers)
    k_zero_int<<<(N_NODES + 255) / 256, 256, 0, stream>>>(deg, N_NODES);
    k_hist<<<egrid, EB, 0, stream>>>(dsti, deg);
    k_scan<<<1, 256, 0, stream>>>(deg, offs, cursor);
    k_scatter<<<egrid, EB, 0, stream>>>(dsti, cursor, perm);

    // layer 1
    k_scores1<<<egrid, EB, 0, stream>>>(srci, dsti, as1, ad1, e1);
    k_msum1<<<(N_NODES + 3) / 4, 256, 0, stream>>>(offs, perm, e1, m1, invs1);
    k_agg1<<<N_NODES, 256, 0, stream>>>(offs, perm, srci, e1, m1, invs1, h1, b1, h_act);

    // layer 2
    k_gemm2<<<N_NODES / 16, 128, 0, stream>>>(h_act, W2, h2);
    k_attn2<<<(N_NODES + 3) / 4, 256, 0, stream>>>(h2, as2w, ad2w, as2, ad2);
    k_scores2<<<egrid, EB, 0, stream>>>(srci, dsti, as2, ad2, e2);
    k_msum2<<<(N_NODES + 3) / 4, 256, 0, stream>>>(offs, perm, e2, m2, invs2);
    k_agg2<<<N_NODES, 128, 0, stream>>>(offs, perm, srci, e2, m2, invs2, h2, b2, Wp, bp, out);
}

// Round 2
// 260.903 us; speedup vs baseline: 1.7000x; 1.7000x over previous
//
#include <hip/hip_runtime.h>
#include <math.h>

#define N_NODES 10000
#define E_IN    320000
#define E_TOT   330000   /* E_IN + N self loops */
#define H1      4
#define C       128
#define F1      512      /* H1*C */

// ---------- tiny precompute: A0/A1/D0/D1[h] = W1 rows dotted with att vectors ----------
__global__ __launch_bounds__(512) void k_prep(
    const float* __restrict__ W1, const float* __restrict__ asw,
    const float* __restrict__ adw, float* __restrict__ prep)
{
    int j = threadIdx.x;                  // 0..511, head = j>>7
    float w0 = W1[j], w1 = W1[F1 + j];
    float a = asw[j], d = adw[j];
    float p0 = w0 * a, p1 = w1 * a, q0 = w0 * d, q1 = w1 * d;
    #pragma unroll
    for (int o = 32; o > 0; o >>= 1) {
        p0 += __shfl_down(p0, o); p1 += __shfl_down(p1, o);
        q0 += __shfl_down(q0, o); q1 += __shfl_down(q1, o);
    }
    __shared__ float red[8][4];
    int wave = j >> 6, lane = j & 63;
    if (lane == 0) { red[wave][0] = p0; red[wave][1] = p1; red[wave][2] = q0; red[wave][3] = q1; }
    __syncthreads();
    if (j < 4) {
        prep[j]      = red[2*j][0] + red[2*j+1][0];   // A0[h]
        prep[4 + j]  = red[2*j][1] + red[2*j+1][1];   // A1[h]
        prep[8 + j]  = red[2*j][2] + red[2*j+1][2];   // D0[h]
        prep[12 + j] = red[2*j][3] + red[2*j+1][3];   // D1[h]
    }
}

// ---------- per-node attention halves for layer 1: as1/ad1 = x @ (2x4) ----------
__global__ void k_as1(const float* __restrict__ x, const float* __restrict__ prep,
                      float4* __restrict__ as1v, float4* __restrict__ ad1v)
{
    int n = blockIdx.x * blockDim.x + threadIdx.x;
    if (n >= N_NODES) return;
    float x0 = x[2*n], x1 = x[2*n+1];
    float4 A0 = *(const float4*)(prep);
    float4 A1 = *(const float4*)(prep + 4);
    float4 D0 = *(const float4*)(prep + 8);
    float4 D1 = *(const float4*)(prep + 12);
    as1v[n] = make_float4(x0*A0.x + x1*A1.x, x0*A0.y + x1*A1.y,
                          x0*A0.z + x1*A1.z, x0*A0.w + x1*A1.w);
    ad1v[n] = make_float4(x0*D0.x + x1*D1.x, x0*D0.y + x1*D1.y,
                          x0*D0.z + x1*D1.z, x0*D0.w + x1*D1.w);
}

// ---------------- CSR build: histogram -> scan -> scatter (stores src ids) ----------------
__global__ void k_zero_int(int* __restrict__ p, int n) {
    int i = blockIdx.x * blockDim.x + threadIdx.x;
    if (i < n) p[i] = 0;
}

__global__ void k_hist(const int* __restrict__ dsti, int* __restrict__ deg) {
    int t = blockIdx.x * blockDim.x + threadIdx.x;
    if (t >= E_TOT) return;
    int d = (t < E_IN) ? dsti[t] : (t - E_IN);
    atomicAdd(&deg[d], 1);
}

__global__ __launch_bounds__(256) void k_scan(
    const int* __restrict__ deg, int* __restrict__ offs, int* __restrict__ cursor)
{
    __shared__ int part[256];
    int tid = threadIdx.x;
    const int CH = (N_NODES + 255) / 256;   // 40
    int start = tid * CH;
    int sum = 0;
    for (int i = 0; i < CH; ++i) { int idx = start + i; if (idx < N_NODES) sum += deg[idx]; }
    part[tid] = sum;
    __syncthreads();
    for (int off = 1; off < 256; off <<= 1) {
        int v = (tid >= off) ? part[tid - off] : 0;
        __syncthreads();
        part[tid] += v;
        __syncthreads();
    }
    int base = (tid == 0) ? 0 : part[tid - 1];
    for (int i = 0; i < CH; ++i) {
        int idx = start + i;
        if (idx < N_NODES) { offs[idx] = base; cursor[idx] = base; base += deg[idx]; }
    }
    if (tid == 255) offs[N_NODES] = base;   // == E_TOT
}

__global__ void k_scatter(const int* __restrict__ srci, const int* __restrict__ dsti,
                          int* __restrict__ cursor, int* __restrict__ scsr) {
    int t = blockIdx.x * blockDim.x + threadIdx.x;
    if (t >= E_TOT) return;
    int d = (t < E_IN) ? dsti[t] : (t - E_IN);
    int s = (t < E_IN) ? srci[t] : (t - E_IN);
    int pos = atomicAdd(&cursor[d], 1);
    scsr[pos] = s;
}

// ---------- layer-1 fused: scores + softmax + 2-dim weighted-x aggregation ----------
// wxn[n][2h+k] = (sum_e alpha[e,h] * x[s_e,k])   (alpha normalized: folded 1/sum)
__global__ __launch_bounds__(256) void k_fused1(
    const int* __restrict__ offs, const int* __restrict__ scsr,
    const float4* __restrict__ as1v, const float4* __restrict__ ad1v,
    const float2* __restrict__ xv, float* __restrict__ wxn)
{
    int node = blockIdx.x * 4 + (threadIdx.x >> 6);
    int lane = threadIdx.x & 63;
    if (node >= N_NODES) return;
    int beg = offs[node], end = offs[node + 1];
    float4 ad = ad1v[node];
    float m0 = -1e30f, m1 = -1e30f, m2 = -1e30f, m3 = -1e30f;
    for (int i = beg + lane; i < end; i += 64) {
        float4 a = as1v[scsr[i]];
        float e0 = a.x + ad.x; e0 = e0 > 0.f ? e0 : 0.2f*e0;
        float e1 = a.y + ad.y; e1 = e1 > 0.f ? e1 : 0.2f*e1;
        float e2 = a.z + ad.z; e2 = e2 > 0.f ? e2 : 0.2f*e2;
        float e3 = a.w + ad.w; e3 = e3 > 0.f ? e3 : 0.2f*e3;
        m0 = fmaxf(m0, e0); m1 = fmaxf(m1, e1); m2 = fmaxf(m2, e2); m3 = fmaxf(m3, e3);
    }
    #pragma unroll
    for (int o = 1; o < 64; o <<= 1) {
        m0 = fmaxf(m0, __shfl_xor(m0, o)); m1 = fmaxf(m1, __shfl_xor(m1, o));
        m2 = fmaxf(m2, __shfl_xor(m2, o)); m3 = fmaxf(m3, __shfl_xor(m3, o));
    }
    float s0 = 0.f, s1 = 0.f, s2 = 0.f, s3 = 0.f;
    float w00 = 0.f, w01 = 0.f, w10 = 0.f, w11 = 0.f;
    float w20 = 0.f, w21 = 0.f, w30 = 0.f, w31 = 0.f;
    for (int i = beg + lane; i < end; i += 64) {
        int s = scsr[i];
        float4 a = as1v[s];
        float2 xs = xv[s];
        float e0 = a.x + ad.x; e0 = e0 > 0.f ? e0 : 0.2f*e0;
        float e1 = a.y + ad.y; e1 = e1 > 0.f ? e1 : 0.2f*e1;
        float e2 = a.z + ad.z; e2 = e2 > 0.f ? e2 : 0.2f*e2;
        float e3 = a.w + ad.w; e3 = e3 > 0.f ? e3 : 0.2f*e3;
        float p0 = __expf(e0 - m0), p1 = __expf(e1 - m1);
        float p2 = __expf(e2 - m2), p3 = __expf(e3 - m3);
        s0 += p0; s1 += p1; s2 += p2; s3 += p3;
        w00 += p0*xs.x; w01 += p0*xs.y; w10 += p1*xs.x; w11 += p1*xs.y;
        w20 += p2*xs.x; w21 += p2*xs.y; w30 += p3*xs.x; w31 += p3*xs.y;
    }
    #pragma unroll
    for (int o = 1; o < 64; o <<= 1) {
        s0 += __shfl_xor(s0, o); s1 += __shfl_xor(s1, o);
        s2 += __shfl_xor(s2, o); s3 += __shfl_xor(s3, o);
        w00 += __shfl_xor(w00, o); w01 += __shfl_xor(w01, o);
        w10 += __shfl_xor(w10, o); w11 += __shfl_xor(w11, o);
        w20 += __shfl_xor(w20, o); w21 += __shfl_xor(w21, o);
        w30 += __shfl_xor(w30, o); w31 += __shfl_xor(w31, o);
    }
    if (lane == 0) {
        float i0 = 1.f/(s0 + 1e-16f), i1 = 1.f/(s1 + 1e-16f);
        float i2 = 1.f/(s2 + 1e-16f), i3 = 1.f/(s3 + 1e-16f);
        float4* W = (float4*)(wxn + node*8);
        W[0] = make_float4(w00*i0, w01*i0, w10*i1, w11*i1);
        W[1] = make_float4(w20*i2, w21*i2, w30*i3, w31*i3);
    }
}

// ---------- layer-2 GEMM fused with layer-1 expansion: h2 = relu(wxn⊗W1+b1) @ W2 ----------
__global__ __launch_bounds__(128) void k_gemm2f(
    const float* __restrict__ wxn, const float* __restrict__ W1,
    const float* __restrict__ b1, const float* __restrict__ W2,
    float* __restrict__ h2)
{
    __shared__ float tile[16 * F1];     // 32 KiB
    __shared__ float wls[16 * 8];
    int n0 = blockIdx.x * 16;
    int tid = threadIdx.x;
    wls[tid] = wxn[n0*8 + tid];         // 128 floats exactly
    __syncthreads();
    #pragma unroll
    for (int q = 0; q < 4; ++q) {
        int k = q*128 + tid;            // channel; head h = k>>7 = q (uniform)
        float w1a = W1[k], w1b = W1[F1 + k], bb = b1[k];
        #pragma unroll
        for (int j = 0; j < 16; ++j) {
            float v = wls[j*8 + 2*q] * w1a + wls[j*8 + 2*q + 1] * w1b + bb;
            tile[j*F1 + k] = v > 0.f ? v : 0.f;
        }
    }
    __syncthreads();
    float acc[16];
    #pragma unroll
    for (int j = 0; j < 16; ++j) acc[j] = 0.f;
    for (int k = 0; k < F1; ++k) {
        float w = W2[k * C + tid];
        #pragma unroll
        for (int j = 0; j < 16; ++j) acc[j] += tile[j * F1 + k] * w;
    }
    #pragma unroll
    for (int j = 0; j < 16; ++j) h2[(n0 + j) * C + tid] = acc[j];
}

// ---------------- layer-2 per-node attention halves ----------------
__global__ __launch_bounds__(256) void k_attn2(
    const float* __restrict__ h2, const float* __restrict__ asw,
    const float* __restrict__ adw, float* __restrict__ as2, float* __restrict__ ad2)
{
    int node = blockIdx.x * 4 + (threadIdx.x >> 6);
    int lane = threadIdx.x & 63;
    if (node >= N_NODES) return;
    const float* hr = h2 + node * C;
    float v0 = hr[lane], v1 = hr[64 + lane];
    float ps = v0 * asw[lane] + v1 * asw[64 + lane];
    float pd = v0 * adw[lane] + v1 * adw[64 + lane];
    #pragma unroll
    for (int d = 32; d > 0; d >>= 1) { ps += __shfl_down(ps, d); pd += __shfl_down(pd, d); }
    if (lane == 0) { as2[node] = ps; ad2[node] = pd; }
}

// ---------- layer-2 softmax: writes unnormalized p per CSR slot + 1/sum per node ----------
__global__ __launch_bounds__(256) void k_malpha2(
    const int* __restrict__ offs, const int* __restrict__ scsr,
    const float* __restrict__ as2, const float* __restrict__ ad2,
    float* __restrict__ palpha, float* __restrict__ invs2)
{
    int node = blockIdx.x * 4 + (threadIdx.x >> 6);
    int lane = threadIdx.x & 63;
    if (node >= N_NODES) return;
    int beg = offs[node], end = offs[node + 1];
    float adn = ad2[node];
    float mx = -1e30f;
    for (int i = beg + lane; i < end; i += 64) {
        float e = as2[scsr[i]] + adn; e = e > 0.f ? e : 0.2f*e;
        mx = fmaxf(mx, e);
    }
    #pragma unroll
    for (int o = 1; o < 64; o <<= 1) mx = fmaxf(mx, __shfl_xor(mx, o));
    float sum = 0.f;
    for (int i = beg + lane; i < end; i += 64) {
        float e = as2[scsr[i]] + adn; e = e > 0.f ? e : 0.2f*e;
        float p = __expf(e - mx);
        sum += p;
        palpha[i] = p;
    }
    #pragma unroll
    for (int o = 1; o < 64; o <<= 1) sum += __shfl_xor(sum, o);
    if (lane == 0) invs2[node] = 1.f / (sum + 1e-16f);
}

// ---------- layer-2 aggregation + bias + relu + final projection ----------
__global__ __launch_bounds__(128) void k_agg2f(
    const int* __restrict__ offs, const int* __restrict__ scsr,
    const float* __restrict__ palpha, const float* __restrict__ invs2,
    const float* __restrict__ h2, const float* __restrict__ b2,
    const float* __restrict__ Wp, const float* __restrict__ bp,
    float* __restrict__ out)
{
    int n = blockIdx.x, c = threadIdx.x;
    int beg = offs[n], end = offs[n + 1];
    float acc = 0.f;
    for (int i = beg; i < end; ++i) {
        int s = scsr[i];
        float p = palpha[i];
        acc += p * h2[s * C + c];
    }
    float v = acc * invs2[n] + b2[c];
    v = v > 0.f ? v : 0.f;
    float contrib = v * Wp[c];
    #pragma unroll
    for (int d = 32; d > 0; d >>= 1) contrib += __shfl_down(contrib, d);
    __shared__ float part[2];
    if ((c & 63) == 0) part[c >> 6] = contrib;
    __syncthreads();
    if (c == 0) out[n] = part[0] + part[1] + bp[0];
}

// ---------------- host launcher ----------------
extern "C" void kernel_launch(void* const* d_in, const int* in_sizes, int n_in,
                              void* d_out, int out_size, void* d_ws, size_t ws_size,
                              hipStream_t stream)
{
    const float* x    = (const float*)d_in[0];
    const int*   ei   = (const int*)d_in[1];
    const int*   srci = ei;
    const int*   dsti = ei + E_IN;
    const float* W1   = (const float*)d_in[2];
    const float* as1w = (const float*)d_in[3];
    const float* ad1w = (const float*)d_in[4];
    const float* b1   = (const float*)d_in[5];
    const float* W2   = (const float*)d_in[6];
    const float* as2w = (const float*)d_in[7];
    const float* ad2w = (const float*)d_in[8];
    const float* b2   = (const float*)d_in[9];
    const float* Wp   = (const float*)d_in[10];
    const float* bp   = (const float*)d_in[11];
    float* out = (float*)d_out;

    char* ws = (char*)d_ws;
    size_t off = 0;
    auto alloc = [&](size_t bytes) -> char* {
        char* p = ws + off;
        off = (off + bytes + 255) & ~(size_t)255;
        return p;
    };
    float*  prep   = (float*)alloc(16 * 4);
    float4* as1v   = (float4*)alloc((size_t)N_NODES * 16);
    float4* ad1v   = (float4*)alloc((size_t)N_NODES * 16);
    float*  wxn    = (float*)alloc((size_t)N_NODES * 8 * 4);
    float*  h2     = (float*)alloc((size_t)N_NODES * C * 4);
    float*  as2    = (float*)alloc((size_t)N_NODES * 4);
    float*  ad2    = (float*)alloc((size_t)N_NODES * 4);
    float*  palpha = (float*)alloc((size_t)E_TOT * 4);
    float*  invs2  = (float*)alloc((size_t)N_NODES * 4);
    int*    deg    = (int*)alloc((size_t)N_NODES * 4);
    int*    offs   = (int*)alloc((size_t)(N_NODES + 1) * 4);
    int*    cursor = (int*)alloc((size_t)N_NODES * 4);
    int*    scsr   = (int*)alloc((size_t)E_TOT * 4);

    const int EB = 256;
    const int egrid = (E_TOT + EB - 1) / EB;
    const int ngrid = (N_NODES + 255) / 256;

    k_prep<<<1, 512, 0, stream>>>(W1, as1w, ad1w, prep);
    k_as1<<<ngrid, 256, 0, stream>>>(x, prep, as1v, ad1v);

    // CSR build (reused by both layers)
    k_zero_int<<<ngrid, 256, 0, stream>>>(deg, N_NODES);
    k_hist<<<egrid, EB, 0, stream>>>(dsti, deg);
    k_scan<<<1, 256, 0, stream>>>(deg, offs, cursor);
    k_scatter<<<egrid, EB, 0, stream>>>(srci, dsti, cursor, scsr);

    // layer 1 (2-dim aggregation, normalization folded)
    k_fused1<<<(N_NODES + 3) / 4, 256, 0, stream>>>(offs, scsr, as1v, ad1v,
                                                    (const float2*)x, wxn);

    // layer 2
    k_gemm2f<<<N_NODES / 16, 128, 0, stream>>>(wxn, W1, b1, W2, h2);
    k_attn2<<<(N_NODES + 3) / 4, 256, 0, stream>>>(h2, as2w, ad2w, as2, ad2);
    k_malpha2<<<(N_NODES + 3) / 4, 256, 0, stream>>>(offs, scsr, as2, ad2, palpha, invs2);
    k_agg2f<<<N_NODES, 128, 0, stream>>>(offs, scsr, palpha, invs2, h2, b2, Wp, bp, out);
}

// Round 3
// 218.442 us; speedup vs baseline: 2.0305x; 1.1944x over previous
//
#include <hip/hip_runtime.h>
#include <math.h>

#define N_NODES 10000
#define E_IN    320000
#define E_TOT   330000   /* E_IN + N self loops */
#define H1      4
#define C       128
#define F1      512      /* H1*C */
#define CAP     1024     /* per-node edge cache (degree is Poisson(33), max << 1024) */

// ---------- tiny precompute: A0/A1/D0/D1[h] = W1 rows dotted with att vectors ----------
__global__ __launch_bounds__(512) void k_prep(
    const float* __restrict__ W1, const float* __restrict__ asw,
    const float* __restrict__ adw, float* __restrict__ prep)
{
    int j = threadIdx.x;                  // 0..511, head = j>>7
    float w0 = W1[j], w1 = W1[F1 + j];
    float a = asw[j], d = adw[j];
    float p0 = w0 * a, p1 = w1 * a, q0 = w0 * d, q1 = w1 * d;
    #pragma unroll
    for (int o = 32; o > 0; o >>= 1) {
        p0 += __shfl_down(p0, o); p1 += __shfl_down(p1, o);
        q0 += __shfl_down(q0, o); q1 += __shfl_down(q1, o);
    }
    __shared__ float red[8][4];
    int wave = j >> 6, lane = j & 63;
    if (lane == 0) { red[wave][0] = p0; red[wave][1] = p1; red[wave][2] = q0; red[wave][3] = q1; }
    __syncthreads();
    if (j < 4) {
        prep[j]      = red[2*j][0] + red[2*j+1][0];   // A0[h]
        prep[4 + j]  = red[2*j][1] + red[2*j+1][1];   // A1[h]
        prep[8 + j]  = red[2*j][2] + red[2*j+1][2];   // D0[h]
        prep[12 + j] = red[2*j][3] + red[2*j+1][3];   // D1[h]
    }
}

// ---------- per-node attention halves for layer 1 (+ zero deg for histogram) ----------
__global__ void k_as1z(const float* __restrict__ x, const float* __restrict__ prep,
                       float4* __restrict__ as1v, float4* __restrict__ ad1v,
                       int* __restrict__ deg)
{
    int n = blockIdx.x * blockDim.x + threadIdx.x;
    if (n >= N_NODES) return;
    deg[n] = 0;
    float x0 = x[2*n], x1 = x[2*n+1];
    float4 A0 = *(const float4*)(prep);
    float4 A1 = *(const float4*)(prep + 4);
    float4 D0 = *(const float4*)(prep + 8);
    float4 D1 = *(const float4*)(prep + 12);
    as1v[n] = make_float4(x0*A0.x + x1*A1.x, x0*A0.y + x1*A1.y,
                          x0*A0.z + x1*A1.z, x0*A0.w + x1*A1.w);
    ad1v[n] = make_float4(x0*D0.x + x1*D1.x, x0*D0.y + x1*D1.y,
                          x0*D0.z + x1*D1.z, x0*D0.w + x1*D1.w);
}

// ---------------- CSR build: histogram -> scan -> scatter (stores src ids) ----------------
__global__ void k_hist(const int* __restrict__ dsti, int* __restrict__ deg) {
    int t = blockIdx.x * blockDim.x + threadIdx.x;
    if (t >= E_TOT) return;
    int d = (t < E_IN) ? dsti[t] : (t - E_IN);
    atomicAdd(&deg[d], 1);
}

__global__ __launch_bounds__(256) void k_scan(
    const int* __restrict__ deg, int* __restrict__ offs, int* __restrict__ cursor)
{
    __shared__ int part[256];
    int tid = threadIdx.x;
    const int CH = (N_NODES + 255) / 256;   // 40
    int start = tid * CH;
    int sum = 0;
    for (int i = 0; i < CH; ++i) { int idx = start + i; if (idx < N_NODES) sum += deg[idx]; }
    part[tid] = sum;
    __syncthreads();
    for (int off = 1; off < 256; off <<= 1) {
        int v = (tid >= off) ? part[tid - off] : 0;
        __syncthreads();
        part[tid] += v;
        __syncthreads();
    }
    int base = (tid == 0) ? 0 : part[tid - 1];
    for (int i = 0; i < CH; ++i) {
        int idx = start + i;
        if (idx < N_NODES) { offs[idx] = base; cursor[idx] = base; base += deg[idx]; }
    }
    if (tid == 255) offs[N_NODES] = base;   // == E_TOT
}

__global__ void k_scatter(const int* __restrict__ srci, const int* __restrict__ dsti,
                          int* __restrict__ cursor, int* __restrict__ scsr) {
    int t = blockIdx.x * blockDim.x + threadIdx.x;
    if (t >= E_TOT) return;
    int d = (t < E_IN) ? dsti[t] : (t - E_IN);
    int s = (t < E_IN) ? srci[t] : (t - E_IN);
    int pos = atomicAdd(&cursor[d], 1);
    scsr[pos] = s;
}

// ---------- layer-1 fused: scores + softmax (no max pass) + 2-dim aggregation ----------
__global__ __launch_bounds__(256) void k_fused1(
    const int* __restrict__ offs, const int* __restrict__ scsr,
    const float4* __restrict__ as1v, const float4* __restrict__ ad1v,
    const float2* __restrict__ xv, float* __restrict__ wxn)
{
    int node = blockIdx.x * 4 + (threadIdx.x >> 6);
    int lane = threadIdx.x & 63;
    if (node >= N_NODES) return;
    int beg = offs[node], end = offs[node + 1];
    float4 ad = ad1v[node];
    float s0 = 0.f, s1 = 0.f, s2 = 0.f, s3 = 0.f;
    float w00 = 0.f, w01 = 0.f, w10 = 0.f, w11 = 0.f;
    float w20 = 0.f, w21 = 0.f, w30 = 0.f, w31 = 0.f;
    for (int i = beg + lane; i < end; i += 64) {
        int s = scsr[i];
        float4 a = as1v[s];
        float2 xs = xv[s];
        float e0 = a.x + ad.x; e0 = e0 > 0.f ? e0 : 0.2f*e0;
        float e1 = a.y + ad.y; e1 = e1 > 0.f ? e1 : 0.2f*e1;
        float e2 = a.z + ad.z; e2 = e2 > 0.f ? e2 : 0.2f*e2;
        float e3 = a.w + ad.w; e3 = e3 > 0.f ? e3 : 0.2f*e3;
        float p0 = __expf(e0), p1 = __expf(e1), p2 = __expf(e2), p3 = __expf(e3);
        s0 += p0; s1 += p1; s2 += p2; s3 += p3;
        w00 += p0*xs.x; w01 += p0*xs.y; w10 += p1*xs.x; w11 += p1*xs.y;
        w20 += p2*xs.x; w21 += p2*xs.y; w30 += p3*xs.x; w31 += p3*xs.y;
    }
    #pragma unroll
    for (int o = 1; o < 64; o <<= 1) {
        s0 += __shfl_xor(s0, o); s1 += __shfl_xor(s1, o);
        s2 += __shfl_xor(s2, o); s3 += __shfl_xor(s3, o);
        w00 += __shfl_xor(w00, o); w01 += __shfl_xor(w01, o);
        w10 += __shfl_xor(w10, o); w11 += __shfl_xor(w11, o);
        w20 += __shfl_xor(w20, o); w21 += __shfl_xor(w21, o);
        w30 += __shfl_xor(w30, o); w31 += __shfl_xor(w31, o);
    }
    if (lane == 0) {
        float i0 = 1.f/(s0 + 1e-16f), i1 = 1.f/(s1 + 1e-16f);
        float i2 = 1.f/(s2 + 1e-16f), i3 = 1.f/(s3 + 1e-16f);
        float4* W = (float4*)(wxn + node*8);
        W[0] = make_float4(w00*i0, w01*i0, w10*i1, w11*i1);
        W[1] = make_float4(w20*i2, w21*i2, w30*i3, w31*i3);
    }
}

// ---------- layer-2 GEMM (register-tiled) + fused attn2 epilogue ----------
// tile: 16 nodes x 128 ch, 256 threads, thread = 2 nodes x 4 ch, K chunks of 64
__global__ __launch_bounds__(256) void k_gemm2(
    const float* __restrict__ wxn, const float* __restrict__ W1,
    const float* __restrict__ b1, const float* __restrict__ W2,
    const float* __restrict__ asw, const float* __restrict__ adw,
    float* __restrict__ h2, float* __restrict__ as2, float* __restrict__ ad2)
{
    __shared__ float A_lds[64][16];      // 4 KiB  (k-major, nodes contiguous)
    __shared__ float B_lds[64 * C];      // 32 KiB
    __shared__ float wls[16 * 8];
    int n0 = blockIdx.x * 16;
    int tid = threadIdx.x;
    int cg = tid & 31;                   // channel group: 4*cg .. 4*cg+3
    int ng = tid >> 5;                   // node group:    2*ng, 2*ng+1
    if (tid < 128) wls[tid] = wxn[n0*8 + tid];

    float acc0x = 0.f, acc0y = 0.f, acc0z = 0.f, acc0w = 0.f;
    float acc1x = 0.f, acc1y = 0.f, acc1z = 0.f, acc1w = 0.f;

    int kl = tid >> 2;                   // 0..63  (expansion k within chunk)
    int nq = (tid & 3) * 4;              // 0,4,8,12 (expansion node quad)

    for (int kc = 0; kc < 8; ++kc) {
        __syncthreads();
        // stage B chunk (rows kc*64 .. +64 of W2, contiguous 8192 floats)
        const float* Wsrc = W2 + kc * (64 * C);
        #pragma unroll
        for (int i = tid * 4; i < 64 * C; i += 1024)
            *(float4*)(B_lds + i) = *(const float4*)(Wsrc + i);
        // expand A chunk: g[n,k] = relu(wx0*W1[0,kg] + wx1*W1[1,kg] + b1[kg])
        {
            int kg = kc * 64 + kl;
            int h2i = (kc >> 1) * 2;      // 2*h, h = kg>>7 uniform per chunk
            float w1a = W1[kg], w1b = W1[F1 + kg], bb = b1[kg];
            #pragma unroll
            for (int u = 0; u < 4; ++u) {
                int n = nq + u;
                float v = wls[n*8 + h2i] * w1a + wls[n*8 + h2i + 1] * w1b + bb;
                A_lds[kl][n] = v > 0.f ? v : 0.f;
            }
        }
        __syncthreads();
        #pragma unroll 8
        for (int k = 0; k < 64; ++k) {
            float2 a = *(const float2*)&A_lds[k][2*ng];
            float4 b = *(const float4*)&B_lds[k*C + 4*cg];
            acc0x += a.x*b.x; acc0y += a.x*b.y; acc0z += a.x*b.z; acc0w += a.x*b.w;
            acc1x += a.y*b.x; acc1y += a.y*b.y; acc1z += a.y*b.z; acc1w += a.y*b.w;
        }
    }
    // write h2
    int r0 = n0 + 2*ng;
    *(float4*)(h2 + (size_t)r0*C + 4*cg)     = make_float4(acc0x, acc0y, acc0z, acc0w);
    *(float4*)(h2 + (size_t)(r0+1)*C + 4*cg) = make_float4(acc1x, acc1y, acc1z, acc1w);
    // fused attn2: per-node dots with att vectors
    float4 av = *(const float4*)(asw + 4*cg);
    float4 dv = *(const float4*)(adw + 4*cg);
    float ps0 = acc0x*av.x + acc0y*av.y + acc0z*av.z + acc0w*av.w;
    float pd0 = acc0x*dv.x + acc0y*dv.y + acc0z*dv.z + acc0w*dv.w;
    float ps1 = acc1x*av.x + acc1y*av.y + acc1z*av.z + acc1w*av.w;
    float pd1 = acc1x*dv.x + acc1y*dv.y + acc1z*dv.z + acc1w*dv.w;
    #pragma unroll
    for (int o = 1; o < 32; o <<= 1) {       // reduce across the 32 channel groups
        ps0 += __shfl_xor(ps0, o); pd0 += __shfl_xor(pd0, o);
        ps1 += __shfl_xor(ps1, o); pd1 += __shfl_xor(pd1, o);
    }
    if (cg == 0) {
        as2[r0] = ps0; ad2[r0] = pd0;
        as2[r0+1] = ps1; ad2[r0+1] = pd1;
    }
}

// ---------- layer-2 fused: softmax (no max) + aggregation + bias/relu + projection ----------
__global__ __launch_bounds__(128) void k_agg2(
    const int* __restrict__ offs, const int* __restrict__ scsr,
    const float* __restrict__ as2, const float* __restrict__ ad2,
    const float* __restrict__ h2, const float* __restrict__ b2,
    const float* __restrict__ Wp, const float* __restrict__ bp,
    float* __restrict__ out)
{
    __shared__ float p_lds[CAP];
    __shared__ int   s_lds[CAP];
    __shared__ float red[2];
    int n = blockIdx.x, tid = threadIdx.x;
    int beg = offs[n], end = offs[n + 1];
    int degn = end - beg;
    int cnt = degn < CAP ? degn : CAP;
    float adn = ad2[n];
    float psum = 0.f;
    for (int j = tid; j < cnt; j += 128) {
        int s = scsr[beg + j];
        float e = as2[s] + adn; e = e > 0.f ? e : 0.2f*e;
        float p = __expf(e);
        p_lds[j] = p; s_lds[j] = s;
        psum += p;
    }
    for (int j = CAP + tid; j < degn; j += 128) {      // overflow tail (never in practice)
        int s = scsr[beg + j];
        float e = as2[s] + adn; e = e > 0.f ? e : 0.2f*e;
        psum += __expf(e);
    }
    #pragma unroll
    for (int o = 32; o > 0; o >>= 1) psum += __shfl_down(psum, o);
    if ((tid & 63) == 0) red[tid >> 6] = psum;
    __syncthreads();
    float inv = 1.f / (red[0] + red[1] + 1e-16f);
    // phase 2: channel-parallel aggregation
    int c = tid;
    float acc = 0.f;
    for (int j = 0; j < cnt; ++j)
        acc += p_lds[j] * h2[(size_t)s_lds[j]*C + c];
    for (int j = CAP; j < degn; ++j) {
        int s = scsr[beg + j];
        float e = as2[s] + adn; e = e > 0.f ? e : 0.2f*e;
        acc += __expf(e) * h2[(size_t)s*C + c];
    }
    float v = acc * inv + b2[c];
    v = v > 0.f ? v : 0.f;
    float contrib = v * Wp[c];
    #pragma unroll
    for (int o = 32; o > 0; o >>= 1) contrib += __shfl_down(contrib, o);
    __syncthreads();
    if ((tid & 63) == 0) red[tid >> 6] = contrib;
    __syncthreads();
    if (tid == 0) out[n] = red[0] + red[1] + bp[0];
}

// ---------------- host launcher ----------------
extern "C" void kernel_launch(void* const* d_in, const int* in_sizes, int n_in,
                              void* d_out, int out_size, void* d_ws, size_t ws_size,
                              hipStream_t stream)
{
    const float* x    = (const float*)d_in[0];
    const int*   ei   = (const int*)d_in[1];
    const int*   srci = ei;
    const int*   dsti = ei + E_IN;
    const float* W1   = (const float*)d_in[2];
    const float* as1w = (const float*)d_in[3];
    const float* ad1w = (const float*)d_in[4];
    const float* b1   = (const float*)d_in[5];
    const float* W2   = (const float*)d_in[6];
    const float* as2w = (const float*)d_in[7];
    const float* ad2w = (const float*)d_in[8];
    const float* b2   = (const float*)d_in[9];
    const float* Wp   = (const float*)d_in[10];
    const float* bp   = (const float*)d_in[11];
    float* out = (float*)d_out;

    char* ws = (char*)d_ws;
    size_t off = 0;
    auto alloc = [&](size_t bytes) -> char* {
        char* p = ws + off;
        off = (off + bytes + 255) & ~(size_t)255;
        return p;
    };
    float*  prep   = (float*)alloc(16 * 4);
    float4* as1v   = (float4*)alloc((size_t)N_NODES * 16);
    float4* ad1v   = (float4*)alloc((size_t)N_NODES * 16);
    float*  wxn    = (float*)alloc((size_t)N_NODES * 8 * 4);
    float*  h2     = (float*)alloc((size_t)N_NODES * C * 4);
    float*  as2    = (float*)alloc((size_t)N_NODES * 4);
    float*  ad2    = (float*)alloc((size_t)N_NODES * 4);
    int*    deg    = (int*)alloc((size_t)N_NODES * 4);
    int*    offs   = (int*)alloc((size_t)(N_NODES + 1) * 4);
    int*    cursor = (int*)alloc((size_t)N_NODES * 4);
    int*    scsr   = (int*)alloc((size_t)E_TOT * 4);

    const int EB = 256;
    const int egrid = (E_TOT + EB - 1) / EB;
    const int ngrid = (N_NODES + 255) / 256;

    k_prep<<<1, 512, 0, stream>>>(W1, as1w, ad1w, prep);
    k_as1z<<<ngrid, 256, 0, stream>>>(x, prep, as1v, ad1v, deg);

    // CSR build (reused by both layers)
    k_hist<<<egrid, EB, 0, stream>>>(dsti, deg);
    k_scan<<<1, 256, 0, stream>>>(deg, offs, cursor);
    k_scatter<<<egrid, EB, 0, stream>>>(srci, dsti, cursor, scsr);

    // layer 1 (2-dim aggregation, single pass)
    k_fused1<<<(N_NODES + 3) / 4, 256, 0, stream>>>(offs, scsr, as1v, ad1v,
                                                    (const float2*)x, wxn);

    // layer 2
    k_gemm2<<<N_NODES / 16, 256, 0, stream>>>(wxn, W1, b1, W2, as2w, ad2w, h2, as2, ad2);
    k_agg2<<<N_NODES, 128, 0, stream>>>(offs, scsr, as2, ad2, h2, b2, Wp, bp, out);
}

// Round 5
// 217.792 us; speedup vs baseline: 2.0366x; 1.0030x over previous
//
#include <hip/hip_runtime.h>
#include <hip/hip_fp16.h>
#include <math.h>

#define N_NODES 10000
#define E_IN    320000
#define E_TOT   330000   /* E_IN + N self loops */
#define H1      4
#define C       128
#define F1      512      /* H1*C */

// ---------- fused: prep (W1·att dots, recomputed per block) + as1/ad1 + deg zero ----------
__global__ __launch_bounds__(256) void k_as1z(
    const float* __restrict__ x, const float* __restrict__ W1,
    const float* __restrict__ asw, const float* __restrict__ adw,
    float4* __restrict__ as1v, float4* __restrict__ ad1v, int* __restrict__ deg)
{
    __shared__ float red[4][8];
    __shared__ float prep_s[16];   // A0[4] A1[4] D0[4] D1[4]
    int tid = threadIdx.x;
    {
        int j = tid;              // head h = j>>7 in {0,1}
        int j2 = tid + 256;       // head in {2,3}
        float w0a = W1[j],  w1a = W1[F1 + j];
        float w0b = W1[j2], w1b = W1[F1 + j2];
        float aa = asw[j], dd = adw[j], ab = asw[j2], db = adw[j2];
        float q0 = w0a*aa, q1 = w1a*aa, q2 = w0a*dd, q3 = w1a*dd;
        float q4 = w0b*ab, q5 = w1b*ab, q6 = w0b*db, q7 = w1b*db;
        #pragma unroll
        for (int o = 32; o > 0; o >>= 1) {
            q0 += __shfl_down(q0, o); q1 += __shfl_down(q1, o);
            q2 += __shfl_down(q2, o); q3 += __shfl_down(q3, o);
            q4 += __shfl_down(q4, o); q5 += __shfl_down(q5, o);
            q6 += __shfl_down(q6, o); q7 += __shfl_down(q7, o);
        }
        int wave = tid >> 6, lane = tid & 63;
        if (lane == 0) {
            red[wave][0] = q0; red[wave][1] = q1; red[wave][2] = q2; red[wave][3] = q3;
            red[wave][4] = q4; red[wave][5] = q5; red[wave][6] = q6; red[wave][7] = q7;
        }
        __syncthreads();
        if (tid < 16) {
            int t = tid >> 2;          // quantity: 0=A0 1=A1 2=D0 3=D1
            int h = tid & 3;
            int w0 = (h & 1) * 2;      // odd heads live in waves 2,3
            int r  = t + (h >> 1) * 4; // heads 2,3 use q[4..7]
            prep_s[t*4 + h] = red[w0][r] + red[w0+1][r];
        }
        __syncthreads();
    }
    int n = blockIdx.x * 256 + tid;
    if (n >= N_NODES) return;
    deg[n] = 0;
    float x0 = x[2*n], x1 = x[2*n+1];
    float4 A0 = *(const float4*)(prep_s);
    float4 A1 = *(const float4*)(prep_s + 4);
    float4 D0 = *(const float4*)(prep_s + 8);
    float4 D1 = *(const float4*)(prep_s + 12);
    as1v[n] = make_float4(x0*A0.x + x1*A1.x, x0*A0.y + x1*A1.y,
                          x0*A0.z + x1*A1.z, x0*A0.w + x1*A1.w);
    ad1v[n] = make_float4(x0*D0.x + x1*D1.x, x0*D0.y + x1*D1.y,
                          x0*D0.z + x1*D1.z, x0*D0.w + x1*D1.w);
}

// ---------------- CSR build ----------------
__global__ void k_hist(const int* __restrict__ dsti, int* __restrict__ deg) {
    int t = blockIdx.x * blockDim.x + threadIdx.x;
    if (t >= E_TOT) return;
    int d = (t < E_IN) ? dsti[t] : (t - E_IN);
    atomicAdd(&deg[d], 1);
}

__global__ __launch_bounds__(256) void k_scan(
    const int* __restrict__ deg, int* __restrict__ offs, int* __restrict__ cursor)
{
    __shared__ int part[256];
    int tid = threadIdx.x;
    const int CH = (N_NODES + 255) / 256;   // 40
    int start = tid * CH;
    int sum = 0;
    for (int i = 0; i < CH; ++i) { int idx = start + i; if (idx < N_NODES) sum += deg[idx]; }
    part[tid] = sum;
    __syncthreads();
    for (int off = 1; off < 256; off <<= 1) {
        int v = (tid >= off) ? part[tid - off] : 0;
        __syncthreads();
        part[tid] += v;
        __syncthreads();
    }
    int base = (tid == 0) ? 0 : part[tid - 1];
    for (int i = 0; i < CH; ++i) {
        int idx = start + i;
        if (idx < N_NODES) { offs[idx] = base; cursor[idx] = base; base += deg[idx]; }
    }
    if (tid == 255) offs[N_NODES] = base;
}

__global__ void k_scatter(const int* __restrict__ srci, const int* __restrict__ dsti,
                          int* __restrict__ cursor, int* __restrict__ scsr) {
    int t = blockIdx.x * blockDim.x + threadIdx.x;
    if (t >= E_TOT) return;
    int d = (t < E_IN) ? dsti[t] : (t - E_IN);
    int s = (t < E_IN) ? srci[t] : (t - E_IN);
    int pos = atomicAdd(&cursor[d], 1);
    scsr[pos] = s;
}

// ---------- layer-1 fused: scores + softmax (no max) + 2-dim aggregation ----------
// 16 lanes per node (avg degree ~33 -> ~2 iterations)
__global__ __launch_bounds__(256) void k_fused1(
    const int* __restrict__ offs, const int* __restrict__ scsr,
    const float4* __restrict__ as1v, const float4* __restrict__ ad1v,
    const float2* __restrict__ xv, float* __restrict__ wxn)
{
    int node = blockIdx.x * 16 + (threadIdx.x >> 4);
    int sub = threadIdx.x & 15;
    int beg = offs[node], end = offs[node + 1];
    float4 ad = ad1v[node];
    float s0 = 0.f, s1 = 0.f, s2 = 0.f, s3 = 0.f;
    float w00 = 0.f, w01 = 0.f, w10 = 0.f, w11 = 0.f;
    float w20 = 0.f, w21 = 0.f, w30 = 0.f, w31 = 0.f;
    for (int i = beg + sub; i < end; i += 16) {
        int s = scsr[i];
        float4 a = as1v[s];
        float2 xs = xv[s];
        float e0 = a.x + ad.x; e0 = e0 > 0.f ? e0 : 0.2f*e0;
        float e1 = a.y + ad.y; e1 = e1 > 0.f ? e1 : 0.2f*e1;
        float e2 = a.z + ad.z; e2 = e2 > 0.f ? e2 : 0.2f*e2;
        float e3 = a.w + ad.w; e3 = e3 > 0.f ? e3 : 0.2f*e3;
        float p0 = __expf(e0), p1 = __expf(e1), p2 = __expf(e2), p3 = __expf(e3);
        s0 += p0; s1 += p1; s2 += p2; s3 += p3;
        w00 += p0*xs.x; w01 += p0*xs.y; w10 += p1*xs.x; w11 += p1*xs.y;
        w20 += p2*xs.x; w21 += p2*xs.y; w30 += p3*xs.x; w31 += p3*xs.y;
    }
    #pragma unroll
    for (int o = 1; o < 16; o <<= 1) {
        s0 += __shfl_xor(s0, o); s1 += __shfl_xor(s1, o);
        s2 += __shfl_xor(s2, o); s3 += __shfl_xor(s3, o);
        w00 += __shfl_xor(w00, o); w01 += __shfl_xor(w01, o);
        w10 += __shfl_xor(w10, o); w11 += __shfl_xor(w11, o);
        w20 += __shfl_xor(w20, o); w21 += __shfl_xor(w21, o);
        w30 += __shfl_xor(w30, o); w31 += __shfl_xor(w31, o);
    }
    if (sub == 0) {
        float i0 = 1.f/(s0 + 1e-16f), i1 = 1.f/(s1 + 1e-16f);
        float i2 = 1.f/(s2 + 1e-16f), i3 = 1.f/(s3 + 1e-16f);
        float4* W = (float4*)(wxn + node*8);
        W[0] = make_float4(w00*i0, w01*i0, w10*i1, w11*i1);
        W[1] = make_float4(w20*i2, w21*i2, w30*i3, w31*i3);
    }
}

// ---------- layer-2 GEMM (16 nodes x 128 ch, thread = 2n x 4c) + attn2 epilogue ----------
// h2 written as fp16 for the aggregation gather; attention scores from fp32 accs.
__global__ __launch_bounds__(256) void k_gemm2(
    const float* __restrict__ wxn, const float* __restrict__ W1,
    const float* __restrict__ b1, const float* __restrict__ W2,
    const float* __restrict__ asw, const float* __restrict__ adw,
    __half* __restrict__ h2h, float* __restrict__ as2, float* __restrict__ ad2)
{
    __shared__ float B_lds[64 * C];     // 32 KiB
    __shared__ float A_lds[64 * 16];    // 4 KiB, [k][n]
    __shared__ float wls[16 * 9];       // padded stride 9
    int tid = threadIdx.x;
    int n0 = blockIdx.x * 16;
    if (tid < 128) {
        int n = tid >> 3, q = tid & 7;
        wls[n*9 + q] = wxn[(n0 + n)*8 + q];
    }
    int cg = tid & 31;                  // channels 4cg..4cg+3
    int ng = tid >> 5;                  // nodes 2ng, 2ng+1
    int e_n = tid & 15, e_kq = tid >> 4;
    float acc00 = 0.f, acc01 = 0.f, acc02 = 0.f, acc03 = 0.f;
    float acc10 = 0.f, acc11 = 0.f, acc12 = 0.f, acc13 = 0.f;

    for (int kc = 0; kc < 8; ++kc) {
        __syncthreads();
        const float* Wsrc = W2 + kc * (64 * C);
        #pragma unroll
        for (int i = 0; i < 8; ++i)
            *(float4*)(B_lds + tid*4 + i*1024) = *(const float4*)(Wsrc + tid*4 + i*1024);
        int h2i = (kc >> 1) * 2;        // head*2, uniform per chunk
        float wa = wls[e_n*9 + h2i], wb = wls[e_n*9 + h2i + 1];
        #pragma unroll
        for (int u = 0; u < 4; ++u) {
            int kl = e_kq*4 + u;
            int kg = kc*64 + kl;
            float v = wa * W1[kg] + wb * W1[F1 + kg] + b1[kg];
            A_lds[kl*16 + e_n] = v > 0.f ? v : 0.f;
        }
        __syncthreads();
        #pragma unroll 8
        for (int k = 0; k < 64; ++k) {
            float2 a = *(const float2*)(A_lds + k*16 + 2*ng);
            float4 b = *(const float4*)(B_lds + k*C + 4*cg);
            acc00 += a.x*b.x; acc01 += a.x*b.y; acc02 += a.x*b.z; acc03 += a.x*b.w;
            acc10 += a.y*b.x; acc11 += a.y*b.y; acc12 += a.y*b.z; acc13 += a.y*b.w;
        }
    }
    int r0 = n0 + 2*ng;
    {
        __half2 lo0 = __floats2half2_rn(acc00, acc01);
        __half2 hi0 = __floats2half2_rn(acc02, acc03);
        __half2 lo1 = __floats2half2_rn(acc10, acc11);
        __half2 hi1 = __floats2half2_rn(acc12, acc13);
        *(uint2*)(h2h + (size_t)r0*C + 4*cg)     = make_uint2(*(uint*)&lo0, *(uint*)&hi0);
        *(uint2*)(h2h + (size_t)(r0+1)*C + 4*cg) = make_uint2(*(uint*)&lo1, *(uint*)&hi1);
    }
    float4 av = *(const float4*)(asw + 4*cg);
    float4 dv = *(const float4*)(adw + 4*cg);
    float ps0 = acc00*av.x + acc01*av.y + acc02*av.z + acc03*av.w;
    float pd0 = acc00*dv.x + acc01*dv.y + acc02*dv.z + acc03*dv.w;
    float ps1 = acc10*av.x + acc11*av.y + acc12*av.z + acc13*av.w;
    float pd1 = acc10*dv.x + acc11*dv.y + acc12*dv.z + acc13*dv.w;
    #pragma unroll
    for (int o = 1; o < 32; o <<= 1) {
        ps0 += __shfl_xor(ps0, o); pd0 += __shfl_xor(pd0, o);
        ps1 += __shfl_xor(ps1, o); pd1 += __shfl_xor(pd1, o);
    }
    if (cg == 0) {
        as2[r0] = ps0;   ad2[r0] = pd0;
        as2[r0+1] = ps1; ad2[r0+1] = pd1;
    }
}

// ---------- layer-2: softmax (no max) + aggregation + bias/relu + projection ----------
// one 64-lane wave per node; p recomputed per lane (broadcast loads), no LDS
__global__ __launch_bounds__(64) void k_agg2(
    const int* __restrict__ offs, const int* __restrict__ scsr,
    const float* __restrict__ as2, const float* __restrict__ ad2,
    const __half* __restrict__ h2h, const float* __restrict__ b2,
    const float* __restrict__ Wp, const float* __restrict__ bp,
    float* __restrict__ out)
{
    int n = blockIdx.x, lane = threadIdx.x;    // lane handles channels 2*lane, 2*lane+1
    int beg = offs[n], end = offs[n + 1];
    float adn = ad2[n];
    float accx = 0.f, accy = 0.f, psum = 0.f;
    for (int i = beg; i < end; ++i) {
        int s = scsr[i];
        float e = as2[s] + adn; e = e > 0.f ? e : 0.2f*e;
        float p = __expf(e);
        psum += p;
        __half2 hv = *(const __half2*)(h2h + (size_t)s*C + 2*lane);
        float2 f = __half22float2(hv);
        accx += p * f.x; accy += p * f.y;
    }
    float inv = 1.f / (psum + 1e-16f);
    float2 bb = *(const float2*)(b2 + 2*lane);
    float2 wp = *(const float2*)(Wp + 2*lane);
    float v0 = accx*inv + bb.x; v0 = v0 > 0.f ? v0 : 0.f;
    float v1 = accy*inv + bb.y; v1 = v1 > 0.f ? v1 : 0.f;
    float contrib = v0*wp.x + v1*wp.y;
    #pragma unroll
    for (int o = 1; o < 64; o <<= 1) contrib += __shfl_xor(contrib, o);
    if (lane == 0) out[n] = contrib + bp[0];
}

// ---------------- host launcher ----------------
extern "C" void kernel_launch(void* const* d_in, const int* in_sizes, int n_in,
                              void* d_out, int out_size, void* d_ws, size_t ws_size,
                              hipStream_t stream)
{
    const float* x    = (const float*)d_in[0];
    const int*   ei   = (const int*)d_in[1];
    const int*   srci = ei;
    const int*   dsti = ei + E_IN;
    const float* W1   = (const float*)d_in[2];
    const float* as1w = (const float*)d_in[3];
    const float* ad1w = (const float*)d_in[4];
    const float* b1   = (const float*)d_in[5];
    const float* W2   = (const float*)d_in[6];
    const float* as2w = (const float*)d_in[7];
    const float* ad2w = (const float*)d_in[8];
    const float* b2   = (const float*)d_in[9];
    const float* Wp   = (const float*)d_in[10];
    const float* bp   = (const float*)d_in[11];
    float* out = (float*)d_out;

    char* ws = (char*)d_ws;
    size_t off = 0;
    auto alloc = [&](size_t bytes) -> char* {
        char* p = ws + off;
        off = (off + bytes + 255) & ~(size_t)255;
        return p;
    };
    float4* as1v   = (float4*)alloc((size_t)N_NODES * 16);
    float4* ad1v   = (float4*)alloc((size_t)N_NODES * 16);
    float*  wxn    = (float*)alloc((size_t)N_NODES * 8 * 4);
    __half* h2h    = (__half*)alloc((size_t)N_NODES * C * 2);
    float*  as2    = (float*)alloc((size_t)N_NODES * 4);
    float*  ad2    = (float*)alloc((size_t)N_NODES * 4);
    int*    deg    = (int*)alloc((size_t)N_NODES * 4);
    int*    offs   = (int*)alloc((size_t)(N_NODES + 1) * 4);
    int*    cursor = (int*)alloc((size_t)N_NODES * 4);
    int*    scsr   = (int*)alloc((size_t)E_TOT * 4);

    const int EB = 256;
    const int egrid = (E_TOT + EB - 1) / EB;
    const int ngrid = (N_NODES + 255) / 256;

    k_as1z<<<ngrid, 256, 0, stream>>>(x, W1, as1w, ad1w, as1v, ad1v, deg);
    k_hist<<<egrid, EB, 0, stream>>>(dsti, deg);
    k_scan<<<1, 256, 0, stream>>>(deg, offs, cursor);
    k_scatter<<<egrid, EB, 0, stream>>>(srci, dsti, cursor, scsr);
    k_fused1<<<N_NODES / 16, 256, 0, stream>>>(offs, scsr, as1v, ad1v,
                                               (const float2*)x, wxn);
    k_gemm2<<<N_NODES / 16, 256, 0, stream>>>(wxn, W1, b1, W2, as2w, ad2w, h2h, as2, ad2);
    k_agg2<<<N_NODES, 64, 0, stream>>>(offs, scsr, as2, ad2, h2h, b2, Wp, bp, out);
}

// Round 6
// 188.832 us; speedup vs baseline: 2.3489x; 1.1534x over previous
//
#include <hip/hip_runtime.h>
#include <hip/hip_fp16.h>
#include <math.h>

#define N_NODES 10000
#define E_IN    320000
#define E_TOT   330000   /* E_IN + N self loops */
#define H1      4
#define C       128
#define F1      512      /* H1*C */

typedef _Float16 f16x8 __attribute__((ext_vector_type(8)));
typedef float    f32x4 __attribute__((ext_vector_type(4)));

// ---------- fused: prep (W1·att dots, recomputed per block) + as1/ad1 + deg zero ----------
__global__ __launch_bounds__(256) void k_as1z(
    const float* __restrict__ x, const float* __restrict__ W1,
    const float* __restrict__ asw, const float* __restrict__ adw,
    float4* __restrict__ as1v, float4* __restrict__ ad1v, int* __restrict__ deg)
{
    __shared__ float red[4][8];
    __shared__ float prep_s[16];   // A0[4] A1[4] D0[4] D1[4]
    int tid = threadIdx.x;
    {
        int j = tid;              // head h = j>>7 in {0,1}
        int j2 = tid + 256;       // head in {2,3}
        float w0a = W1[j],  w1a = W1[F1 + j];
        float w0b = W1[j2], w1b = W1[F1 + j2];
        float aa = asw[j], dd = adw[j], ab = asw[j2], db = adw[j2];
        float q0 = w0a*aa, q1 = w1a*aa, q2 = w0a*dd, q3 = w1a*dd;
        float q4 = w0b*ab, q5 = w1b*ab, q6 = w0b*db, q7 = w1b*db;
        #pragma unroll
        for (int o = 32; o > 0; o >>= 1) {
            q0 += __shfl_down(q0, o); q1 += __shfl_down(q1, o);
            q2 += __shfl_down(q2, o); q3 += __shfl_down(q3, o);
            q4 += __shfl_down(q4, o); q5 += __shfl_down(q5, o);
            q6 += __shfl_down(q6, o); q7 += __shfl_down(q7, o);
        }
        int wave = tid >> 6, lane = tid & 63;
        if (lane == 0) {
            red[wave][0] = q0; red[wave][1] = q1; red[wave][2] = q2; red[wave][3] = q3;
            red[wave][4] = q4; red[wave][5] = q5; red[wave][6] = q6; red[wave][7] = q7;
        }
        __syncthreads();
        if (tid < 16) {
            int t = tid >> 2;          // quantity: 0=A0 1=A1 2=D0 3=D1
            int h = tid & 3;
            int w0 = (h & 1) * 2;      // odd heads live in waves 2,3
            int r  = t + (h >> 1) * 4; // heads 2,3 use q[4..7]
            prep_s[t*4 + h] = red[w0][r] + red[w0+1][r];
        }
        __syncthreads();
    }
    int n = blockIdx.x * 256 + tid;
    if (n >= N_NODES) return;
    deg[n] = 0;
    float x0 = x[2*n], x1 = x[2*n+1];
    float4 A0 = *(const float4*)(prep_s);
    float4 A1 = *(const float4*)(prep_s + 4);
    float4 D0 = *(const float4*)(prep_s + 8);
    float4 D1 = *(const float4*)(prep_s + 12);
    as1v[n] = make_float4(x0*A0.x + x1*A1.x, x0*A0.y + x1*A1.y,
                          x0*A0.z + x1*A1.z, x0*A0.w + x1*A1.w);
    ad1v[n] = make_float4(x0*D0.x + x1*D1.x, x0*D0.y + x1*D1.y,
                          x0*D0.z + x1*D1.z, x0*D0.w + x1*D1.w);
}

// ---------------- CSR build ----------------
__global__ void k_hist(const int* __restrict__ dsti, int* __restrict__ deg) {
    int t = blockIdx.x * blockDim.x + threadIdx.x;
    if (t >= E_TOT) return;
    int d = (t < E_IN) ? dsti[t] : (t - E_IN);
    atomicAdd(&deg[d], 1);
}

__global__ __launch_bounds__(256) void k_scan(
    const int* __restrict__ deg, int* __restrict__ offs, int* __restrict__ cursor)
{
    __shared__ int part[256];
    int tid = threadIdx.x;
    const int CH = (N_NODES + 255) / 256;   // 40
    int start = tid * CH;
    int sum = 0;
    for (int i = 0; i < CH; ++i) { int idx = start + i; if (idx < N_NODES) sum += deg[idx]; }
    part[tid] = sum;
    __syncthreads();
    for (int off = 1; off < 256; off <<= 1) {
        int v = (tid >= off) ? part[tid - off] : 0;
        __syncthreads();
        part[tid] += v;
        __syncthreads();
    }
    int base = (tid == 0) ? 0 : part[tid - 1];
    for (int i = 0; i < CH; ++i) {
        int idx = start + i;
        if (idx < N_NODES) { offs[idx] = base; cursor[idx] = base; base += deg[idx]; }
    }
    if (tid == 255) offs[N_NODES] = base;
}

__global__ void k_scatter(const int* __restrict__ srci, const int* __restrict__ dsti,
                          int* __restrict__ cursor, int* __restrict__ scsr) {
    int t = blockIdx.x * blockDim.x + threadIdx.x;
    if (t >= E_TOT) return;
    int d = (t < E_IN) ? dsti[t] : (t - E_IN);
    int s = (t < E_IN) ? srci[t] : (t - E_IN);
    int pos = atomicAdd(&cursor[d], 1);
    scsr[pos] = s;
}

// ---------- layer-1 fused: scores + softmax (no max) + 2-dim aggregation ----------
__global__ __launch_bounds__(256) void k_fused1(
    const int* __restrict__ offs, const int* __restrict__ scsr,
    const float4* __restrict__ as1v, const float4* __restrict__ ad1v,
    const float2* __restrict__ xv, float* __restrict__ wxn)
{
    int node = blockIdx.x * 16 + (threadIdx.x >> 4);
    int sub = threadIdx.x & 15;
    int beg = offs[node], end = offs[node + 1];
    float4 ad = ad1v[node];
    float s0 = 0.f, s1 = 0.f, s2 = 0.f, s3 = 0.f;
    float w00 = 0.f, w01 = 0.f, w10 = 0.f, w11 = 0.f;
    float w20 = 0.f, w21 = 0.f, w30 = 0.f, w31 = 0.f;
    for (int i = beg + sub; i < end; i += 16) {
        int s = scsr[i];
        float4 a = as1v[s];
        float2 xs = xv[s];
        float e0 = a.x + ad.x; e0 = e0 > 0.f ? e0 : 0.2f*e0;
        float e1 = a.y + ad.y; e1 = e1 > 0.f ? e1 : 0.2f*e1;
        float e2 = a.z + ad.z; e2 = e2 > 0.f ? e2 : 0.2f*e2;
        float e3 = a.w + ad.w; e3 = e3 > 0.f ? e3 : 0.2f*e3;
        float p0 = __expf(e0), p1 = __expf(e1), p2 = __expf(e2), p3 = __expf(e3);
        s0 += p0; s1 += p1; s2 += p2; s3 += p3;
        w00 += p0*xs.x; w01 += p0*xs.y; w10 += p1*xs.x; w11 += p1*xs.y;
        w20 += p2*xs.x; w21 += p2*xs.y; w30 += p3*xs.x; w31 += p3*xs.y;
    }
    #pragma unroll
    for (int o = 1; o < 16; o <<= 1) {
        s0 += __shfl_xor(s0, o); s1 += __shfl_xor(s1, o);
        s2 += __shfl_xor(s2, o); s3 += __shfl_xor(s3, o);
        w00 += __shfl_xor(w00, o); w01 += __shfl_xor(w01, o);
        w10 += __shfl_xor(w10, o); w11 += __shfl_xor(w11, o);
        w20 += __shfl_xor(w20, o); w21 += __shfl_xor(w21, o);
        w30 += __shfl_xor(w30, o); w31 += __shfl_xor(w31, o);
    }
    if (sub == 0) {
        float i0 = 1.f/(s0 + 1e-16f), i1 = 1.f/(s1 + 1e-16f);
        float i2 = 1.f/(s2 + 1e-16f), i3 = 1.f/(s3 + 1e-16f);
        float4* W = (float4*)(wxn + node*8);
        W[0] = make_float4(w00*i0, w01*i0, w10*i1, w11*i1);
        W[1] = make_float4(w20*i2, w21*i2, w30*i3, w31*i3);
    }
}

// ---------- layer-2 GEMM via fp16 MFMA + attn2 epilogue ----------
// Block: 4 waves, each wave = 16 nodes x 128 ch. W2^T fp16 in LDS (XOR-swizzled).
// MFMA roles: A = W2^T tile (M=channel), B = features generated on the fly (N=node).
__global__ __launch_bounds__(256, 1) void k_gemm2(
    const float* __restrict__ wxn, const float* __restrict__ W1,
    const float* __restrict__ b1, const float* __restrict__ W2,
    const float* __restrict__ asw, const float* __restrict__ adw,
    __half* __restrict__ h2h, float* __restrict__ as2, float* __restrict__ ad2)
{
    __shared__ _Float16 w2t[F1 * C];     // 128 KiB: [col c][k] swizzled
    int tid = threadIdx.x;
    // ---- stage W2 (512x128 f32) -> w2t fp16 transposed, XOR-swizzled ----
    {
        int c0 = (tid & 63) * 2;         // two adjacent cols per thread
        int kh = tid >> 6;               // 0..3 -> k range [kh*128, +128)
        int xr0 = (c0 & 7) << 3;
        int xr1 = ((c0 + 1) & 7) << 3;
        for (int kb = 0; kb < 128; kb += 8) {
            int k0 = kh * 128 + kb;
            f16x8 p0, p1;
            #pragma unroll
            for (int jj = 0; jj < 8; ++jj) {
                float2 w = *(const float2*)(W2 + (k0 + jj) * C + c0);
                p0[jj] = (_Float16)w.x;
                p1[jj] = (_Float16)w.y;
            }
            *(f16x8*)(&w2t[c0 * F1 + (k0 ^ xr0)])       = p0;
            *(f16x8*)(&w2t[(c0 + 1) * F1 + (k0 ^ xr1)]) = p1;
        }
    }
    __syncthreads();

    int wid = tid >> 6, lane = tid & 63;
    int tile = blockIdx.x * 4 + wid;
    if (tile >= N_NODES / 16) return;     // 625 tiles exactly
    int n0w = tile * 16;
    int col = lane & 15;                  // node index within tile
    int krow = (lane >> 4) * 8;           // k offset within 32-chunk
    int qr4 = (lane >> 4) * 4;            // row quad for C/D layout
    int node = n0w + col;

    // per-lane wxn for its node (8 floats, normalized)
    float4 wv0 = *(const float4*)(wxn + node * 8);
    float4 wv1 = *(const float4*)(wxn + node * 8 + 4);

    f32x4 acc[8];
    #pragma unroll
    for (int mt = 0; mt < 8; ++mt) acc[mt] = (f32x4){0.f, 0.f, 0.f, 0.f};

    int xr = (col & 7) << 3;
    const float* W1r0 = W1;
    const float* W1r1 = W1 + F1;

    #pragma unroll
    for (int h = 0; h < 4; ++h) {
        float wa = (h == 0) ? wv0.x : (h == 1) ? wv0.z : (h == 2) ? wv1.x : wv1.z;
        float wb = (h == 0) ? wv0.y : (h == 1) ? wv0.w : (h == 2) ? wv1.y : wv1.w;
        #pragma unroll
        for (int kq = 0; kq < 4; ++kq) {
            int kc = h * 4 + kq;
            int k0 = kc * 32 + krow;
            float4 a0 = *(const float4*)(W1r0 + k0);
            float4 a1 = *(const float4*)(W1r0 + k0 + 4);
            float4 c0 = *(const float4*)(W1r1 + k0);
            float4 c1 = *(const float4*)(W1r1 + k0 + 4);
            float4 b0 = *(const float4*)(b1 + k0);
            float4 b1v = *(const float4*)(b1 + k0 + 4);
            f16x8 bf;
            float v;
            v = wa*a0.x + wb*c0.x + b0.x;  bf[0] = (_Float16)(v > 0.f ? v : 0.f);
            v = wa*a0.y + wb*c0.y + b0.y;  bf[1] = (_Float16)(v > 0.f ? v : 0.f);
            v = wa*a0.z + wb*c0.z + b0.z;  bf[2] = (_Float16)(v > 0.f ? v : 0.f);
            v = wa*a0.w + wb*c0.w + b0.w;  bf[3] = (_Float16)(v > 0.f ? v : 0.f);
            v = wa*a1.x + wb*c1.x + b1v.x; bf[4] = (_Float16)(v > 0.f ? v : 0.f);
            v = wa*a1.y + wb*c1.y + b1v.y; bf[5] = (_Float16)(v > 0.f ? v : 0.f);
            v = wa*a1.z + wb*c1.z + b1v.z; bf[6] = (_Float16)(v > 0.f ? v : 0.f);
            v = wa*a1.w + wb*c1.w + b1v.w; bf[7] = (_Float16)(v > 0.f ? v : 0.f);
            int kbase = col * F1 + (k0 ^ xr);
            #pragma unroll
            for (int mt = 0; mt < 8; ++mt) {
                f16x8 af = *(const f16x8*)(&w2t[mt * 16 * F1 + kbase]);
                acc[mt] = __builtin_amdgcn_mfma_f32_16x16x32_f16(af, bf, acc[mt], 0, 0, 0);
            }
        }
    }

    // ---- epilogue: h2 (fp16) store + attn2 score dots from fp32 accs ----
    float ps = 0.f, pd = 0.f;
    __half* hbase = h2h + (size_t)node * C + qr4;
    #pragma unroll
    for (int mt = 0; mt < 8; ++mt) {
        f32x4 a = acc[mt];
        __half2 lo = __floats2half2_rn(a[0], a[1]);
        __half2 hi = __floats2half2_rn(a[2], a[3]);
        uint2 u; u.x = *(uint*)&lo; u.y = *(uint*)&hi;
        *(uint2*)(hbase + mt * 16) = u;
        float4 av = *(const float4*)(asw + mt * 16 + qr4);
        float4 dv = *(const float4*)(adw + mt * 16 + qr4);
        ps += a[0]*av.x + a[1]*av.y + a[2]*av.z + a[3]*av.w;
        pd += a[0]*dv.x + a[1]*dv.y + a[2]*dv.z + a[3]*dv.w;
    }
    ps += __shfl_xor(ps, 16); ps += __shfl_xor(ps, 32);
    pd += __shfl_xor(pd, 16); pd += __shfl_xor(pd, 32);
    if (lane < 16) { as2[n0w + lane] = ps; ad2[n0w + lane] = pd; }
}

// ---------- layer-2: softmax (no max) + aggregation + bias/relu + projection ----------
// one wave per node, 4 nodes/block; 4-deep unrolled prefetch
__global__ __launch_bounds__(256) void k_agg2(
    const int* __restrict__ offs, const int* __restrict__ scsr,
    const float* __restrict__ as2, const float* __restrict__ ad2,
    const __half* __restrict__ h2h, const float* __restrict__ b2,
    const float* __restrict__ Wp, const float* __restrict__ bp,
    float* __restrict__ out)
{
    int n = blockIdx.x * 4 + (threadIdx.x >> 6);
    int lane = threadIdx.x & 63;          // lane handles channels 2*lane, 2*lane+1
    int beg = offs[n], end = offs[n + 1];
    float adn = ad2[n];
    float accx = 0.f, accy = 0.f, psum = 0.f;
    int i = beg;
    for (; i + 4 <= end; i += 4) {
        int s0 = scsr[i+0], s1 = scsr[i+1], s2 = scsr[i+2], s3 = scsr[i+3];
        float e0 = as2[s0] + adn, e1 = as2[s1] + adn;
        float e2 = as2[s2] + adn, e3 = as2[s3] + adn;
        __half2 q0 = *(const __half2*)(h2h + (size_t)s0*C + 2*lane);
        __half2 q1 = *(const __half2*)(h2h + (size_t)s1*C + 2*lane);
        __half2 q2 = *(const __half2*)(h2h + (size_t)s2*C + 2*lane);
        __half2 q3 = *(const __half2*)(h2h + (size_t)s3*C + 2*lane);
        e0 = e0 > 0.f ? e0 : 0.2f*e0;  float p0 = __expf(e0);
        e1 = e1 > 0.f ? e1 : 0.2f*e1;  float p1 = __expf(e1);
        e2 = e2 > 0.f ? e2 : 0.2f*e2;  float p2 = __expf(e2);
        e3 = e3 > 0.f ? e3 : 0.2f*e3;  float p3 = __expf(e3);
        psum += (p0 + p1) + (p2 + p3);
        float2 f0 = __half22float2(q0), f1 = __half22float2(q1);
        float2 f2 = __half22float2(q2), f3 = __half22float2(q3);
        accx += p0*f0.x + p1*f1.x + p2*f2.x + p3*f3.x;
        accy += p0*f0.y + p1*f1.y + p2*f2.y + p3*f3.y;
    }
    for (; i < end; ++i) {
        int s = scsr[i];
        float e = as2[s] + adn; e = e > 0.f ? e : 0.2f*e;
        float p = __expf(e);
        psum += p;
        __half2 q = *(const __half2*)(h2h + (size_t)s*C + 2*lane);
        float2 f = __half22float2(q);
        accx += p * f.x; accy += p * f.y;
    }
    float inv = 1.f / (psum + 1e-16f);
    float2 bb = *(const float2*)(b2 + 2*lane);
    float2 wp = *(const float2*)(Wp + 2*lane);
    float v0 = accx*inv + bb.x; v0 = v0 > 0.f ? v0 : 0.f;
    float v1 = accy*inv + bb.y; v1 = v1 > 0.f ? v1 : 0.f;
    float contrib = v0*wp.x + v1*wp.y;
    #pragma unroll
    for (int o = 1; o < 64; o <<= 1) contrib += __shfl_xor(contrib, o);
    if (lane == 0) out[n] = contrib + bp[0];
}

// ---------------- host launcher ----------------
extern "C" void kernel_launch(void* const* d_in, const int* in_sizes, int n_in,
                              void* d_out, int out_size, void* d_ws, size_t ws_size,
                              hipStream_t stream)
{
    const float* x    = (const float*)d_in[0];
    const int*   ei   = (const int*)d_in[1];
    const int*   srci = ei;
    const int*   dsti = ei + E_IN;
    const float* W1   = (const float*)d_in[2];
    const float* as1w = (const float*)d_in[3];
    const float* ad1w = (const float*)d_in[4];
    const float* b1   = (const float*)d_in[5];
    const float* W2   = (const float*)d_in[6];
    const float* as2w = (const float*)d_in[7];
    const float* ad2w = (const float*)d_in[8];
    const float* b2   = (const float*)d_in[9];
    const float* Wp   = (const float*)d_in[10];
    const float* bp   = (const float*)d_in[11];
    float* out = (float*)d_out;

    char* ws = (char*)d_ws;
    size_t off = 0;
    auto alloc = [&](size_t bytes) -> char* {
        char* p = ws + off;
        off = (off + bytes + 255) & ~(size_t)255;
        return p;
    };
    float4* as1v   = (float4*)alloc((size_t)N_NODES * 16);
    float4* ad1v   = (float4*)alloc((size_t)N_NODES * 16);
    float*  wxn    = (float*)alloc((size_t)N_NODES * 8 * 4);
    __half* h2h    = (__half*)alloc((size_t)N_NODES * C * 2);
    float*  as2    = (float*)alloc((size_t)N_NODES * 4);
    float*  ad2    = (float*)alloc((size_t)N_NODES * 4);
    int*    deg    = (int*)alloc((size_t)N_NODES * 4);
    int*    offs   = (int*)alloc((size_t)(N_NODES + 1) * 4);
    int*    cursor = (int*)alloc((size_t)N_NODES * 4);
    int*    scsr   = (int*)alloc((size_t)E_TOT * 4);

    const int EB = 256;
    const int egrid = (E_TOT + EB - 1) / EB;
    const int ngrid = (N_NODES + 255) / 256;

    k_as1z<<<ngrid, 256, 0, stream>>>(x, W1, as1w, ad1w, as1v, ad1v, deg);
    k_hist<<<egrid, EB, 0, stream>>>(dsti, deg);
    k_scan<<<1, 256, 0, stream>>>(deg, offs, cursor);
    k_scatter<<<egrid, EB, 0, stream>>>(srci, dsti, cursor, scsr);
    k_fused1<<<N_NODES / 16, 256, 0, stream>>>(offs, scsr, as1v, ad1v,
                                               (const float2*)x, wxn);
    k_gemm2<<<(N_NODES/16 + 3) / 4, 256, 0, stream>>>(wxn, W1, b1, W2, as2w, ad2w,
                                                      h2h, as2, ad2);
    k_agg2<<<N_NODES / 4, 256, 0, stream>>>(offs, scsr, as2, ad2, h2h, b2, Wp, bp, out);
}

// Round 7
// 185.828 us; speedup vs baseline: 2.3869x; 1.0162x over previous
//
#include <hip/hip_runtime.h>
#include <hip/hip_fp16.h>
#include <math.h>

#define N_NODES 10000
#define E_IN    320000
#define E_TOT   330000   /* E_IN + N self loops */
#define H1      4
#define C       128
#define F1      512      /* H1*C */

typedef _Float16 f16x8 __attribute__((ext_vector_type(8)));
typedef float    f32x4 __attribute__((ext_vector_type(4)));

// ---------- fused: prep (W1·att dots, recomputed per block) + as1/ad1 + deg zero ----------
__global__ __launch_bounds__(256) void k_as1z(
    const float* __restrict__ x, const float* __restrict__ W1,
    const float* __restrict__ asw, const float* __restrict__ adw,
    float4* __restrict__ as1v, float4* __restrict__ ad1v, int* __restrict__ deg)
{
    __shared__ float red[4][8];
    __shared__ float prep_s[16];   // A0[4] A1[4] D0[4] D1[4]
    int tid = threadIdx.x;
    {
        int j = tid;              // head h = j>>7 in {0,1}
        int j2 = tid + 256;       // head in {2,3}
        float w0a = W1[j],  w1a = W1[F1 + j];
        float w0b = W1[j2], w1b = W1[F1 + j2];
        float aa = asw[j], dd = adw[j], ab = asw[j2], db = adw[j2];
        float q0 = w0a*aa, q1 = w1a*aa, q2 = w0a*dd, q3 = w1a*dd;
        float q4 = w0b*ab, q5 = w1b*ab, q6 = w0b*db, q7 = w1b*db;
        #pragma unroll
        for (int o = 32; o > 0; o >>= 1) {
            q0 += __shfl_down(q0, o); q1 += __shfl_down(q1, o);
            q2 += __shfl_down(q2, o); q3 += __shfl_down(q3, o);
            q4 += __shfl_down(q4, o); q5 += __shfl_down(q5, o);
            q6 += __shfl_down(q6, o); q7 += __shfl_down(q7, o);
        }
        int wave = tid >> 6, lane = tid & 63;
        if (lane == 0) {
            red[wave][0] = q0; red[wave][1] = q1; red[wave][2] = q2; red[wave][3] = q3;
            red[wave][4] = q4; red[wave][5] = q5; red[wave][6] = q6; red[wave][7] = q7;
        }
        __syncthreads();
        if (tid < 16) {
            int t = tid >> 2;          // quantity: 0=A0 1=A1 2=D0 3=D1
            int h = tid & 3;
            int w0 = (h & 1) * 2;      // odd heads live in waves 2,3
            int r  = t + (h >> 1) * 4; // heads 2,3 use q[4..7]
            prep_s[t*4 + h] = red[w0][r] + red[w0+1][r];
        }
        __syncthreads();
    }
    int n = blockIdx.x * 256 + tid;
    if (n >= N_NODES) return;
    deg[n] = 0;
    float x0 = x[2*n], x1 = x[2*n+1];
    float4 A0 = *(const float4*)(prep_s);
    float4 A1 = *(const float4*)(prep_s + 4);
    float4 D0 = *(const float4*)(prep_s + 8);
    float4 D1 = *(const float4*)(prep_s + 12);
    as1v[n] = make_float4(x0*A0.x + x1*A1.x, x0*A0.y + x1*A1.y,
                          x0*A0.z + x1*A1.z, x0*A0.w + x1*A1.w);
    ad1v[n] = make_float4(x0*D0.x + x1*D1.x, x0*D0.y + x1*D1.y,
                          x0*D0.z + x1*D1.z, x0*D0.w + x1*D1.w);
}

// ---------- W2 f32 -> fp16, transposed + XOR-swizzled: w2h[c*F1 + (k^xr)] = W2[k*C+c] ----------
__global__ __launch_bounds__(256) void k_w2cvt(
    const float* __restrict__ W2, _Float16* __restrict__ w2h)
{
    int t = blockIdx.x * 256 + threadIdx.x;   // 16384 threads x 4 elems
    int e0 = t * 4;
    int c = e0 >> 9;                          // 0..127
    int kk0 = e0 & 511;
    int xr = (c & 7) << 3;
    _Float16 o[4];
    #pragma unroll
    for (int j = 0; j < 4; ++j) {
        int k = (kk0 + j) ^ xr;
        o[j] = (_Float16)W2[k * C + c];
    }
    *(uint2*)(w2h + c * F1 + kk0) = *(uint2*)o;
}

// ---------------- CSR build ----------------
__global__ void k_hist(const int* __restrict__ dsti, int* __restrict__ deg) {
    int t = blockIdx.x * blockDim.x + threadIdx.x;
    if (t >= E_TOT) return;
    int d = (t < E_IN) ? dsti[t] : (t - E_IN);
    atomicAdd(&deg[d], 1);
}

__global__ __launch_bounds__(256) void k_scan(
    const int* __restrict__ deg, int* __restrict__ offs, int* __restrict__ cursor)
{
    __shared__ int part[256];
    int tid = threadIdx.x;
    const int CH = (N_NODES + 255) / 256;   // 40
    int start = tid * CH;
    int sum = 0;
    for (int i = 0; i < CH; ++i) { int idx = start + i; if (idx < N_NODES) sum += deg[idx]; }
    part[tid] = sum;
    __syncthreads();
    for (int off = 1; off < 256; off <<= 1) {
        int v = (tid >= off) ? part[tid - off] : 0;
        __syncthreads();
        part[tid] += v;
        __syncthreads();
    }
    int base = (tid == 0) ? 0 : part[tid - 1];
    for (int i = 0; i < CH; ++i) {
        int idx = start + i;
        if (idx < N_NODES) { offs[idx] = base; cursor[idx] = base; base += deg[idx]; }
    }
    if (tid == 255) offs[N_NODES] = base;
}

__global__ void k_scatter(const int* __restrict__ srci, const int* __restrict__ dsti,
                          int* __restrict__ cursor, int* __restrict__ scsr) {
    int t = blockIdx.x * blockDim.x + threadIdx.x;
    if (t >= E_TOT) return;
    int d = (t < E_IN) ? dsti[t] : (t - E_IN);
    int s = (t < E_IN) ? srci[t] : (t - E_IN);
    int pos = atomicAdd(&cursor[d], 1);
    scsr[pos] = s;
}

// ---------- layer-1 fused: scores + softmax (no max) + 2-dim aggregation ----------
// 16 lanes per node; software-pipelined scsr prefetch
__global__ __launch_bounds__(256) void k_fused1(
    const int* __restrict__ offs, const int* __restrict__ scsr,
    const float4* __restrict__ as1v, const float4* __restrict__ ad1v,
    const float2* __restrict__ xv, float* __restrict__ wxn)
{
    int node = blockIdx.x * 16 + (threadIdx.x >> 4);
    int sub = threadIdx.x & 15;
    int beg = offs[node], end = offs[node + 1];
    float4 ad = ad1v[node];
    float s0 = 0.f, s1 = 0.f, s2 = 0.f, s3 = 0.f;
    float w00 = 0.f, w01 = 0.f, w10 = 0.f, w11 = 0.f;
    float w20 = 0.f, w21 = 0.f, w30 = 0.f, w31 = 0.f;
    int i = beg + sub;
    if (i < end) {
        int s = scsr[i];
        for (;;) {
            float4 a = as1v[s];
            float2 xs = xv[s];
            int inext = i + 16;
            bool more = inext < end;
            int snext = 0;
            if (more) snext = scsr[inext];
            float e0 = a.x + ad.x; e0 = e0 > 0.f ? e0 : 0.2f*e0;
            float e1 = a.y + ad.y; e1 = e1 > 0.f ? e1 : 0.2f*e1;
            float e2 = a.z + ad.z; e2 = e2 > 0.f ? e2 : 0.2f*e2;
            float e3 = a.w + ad.w; e3 = e3 > 0.f ? e3 : 0.2f*e3;
            float p0 = __expf(e0), p1 = __expf(e1), p2 = __expf(e2), p3 = __expf(e3);
            s0 += p0; s1 += p1; s2 += p2; s3 += p3;
            w00 += p0*xs.x; w01 += p0*xs.y; w10 += p1*xs.x; w11 += p1*xs.y;
            w20 += p2*xs.x; w21 += p2*xs.y; w30 += p3*xs.x; w31 += p3*xs.y;
            if (!more) break;
            i = inext; s = snext;
        }
    }
    #pragma unroll
    for (int o = 1; o < 16; o <<= 1) {
        s0 += __shfl_xor(s0, o); s1 += __shfl_xor(s1, o);
        s2 += __shfl_xor(s2, o); s3 += __shfl_xor(s3, o);
        w00 += __shfl_xor(w00, o); w01 += __shfl_xor(w01, o);
        w10 += __shfl_xor(w10, o); w11 += __shfl_xor(w11, o);
        w20 += __shfl_xor(w20, o); w21 += __shfl_xor(w21, o);
        w30 += __shfl_xor(w30, o); w31 += __shfl_xor(w31, o);
    }
    if (sub == 0) {
        float i0 = 1.f/(s0 + 1e-16f), i1 = 1.f/(s1 + 1e-16f);
        float i2 = 1.f/(s2 + 1e-16f), i3 = 1.f/(s3 + 1e-16f);
        float4* W = (float4*)(wxn + node*8);
        W[0] = make_float4(w00*i0, w01*i0, w10*i1, w11*i1);
        W[1] = make_float4(w20*i2, w21*i2, w30*i3, w31*i3);
    }
}

// ---------- layer-2 GEMM via fp16 MFMA + attn2 epilogue ----------
// Block: 4 waves, each wave = 16 nodes x 128 ch. w2h (pre-swizzled fp16) -> LDS linear copy.
__global__ __launch_bounds__(256, 1) void k_gemm2(
    const float* __restrict__ wxn, const float* __restrict__ W1,
    const float* __restrict__ b1, const _Float16* __restrict__ w2h,
    const float* __restrict__ asw, const float* __restrict__ adw,
    __half* __restrict__ h2h, float* __restrict__ as2, float* __restrict__ ad2)
{
    __shared__ _Float16 w2t[F1 * C];     // 128 KiB: [c][k^xr]
    int tid = threadIdx.x;
    #pragma unroll
    for (int it = 0; it < 32; ++it) {
        int idx = (it * 256 + tid) * 8;
        *(f16x8*)(w2t + idx) = *(const f16x8*)(w2h + idx);
    }
    __syncthreads();

    int wid = tid >> 6, lane = tid & 63;
    int tile = blockIdx.x * 4 + wid;
    if (tile >= N_NODES / 16) return;     // 625 tiles exactly
    int n0w = tile * 16;
    int col = lane & 15;                  // node index within tile (and A-row c-index)
    int krow = (lane >> 4) * 8;           // k offset within 32-chunk
    int qr4 = (lane >> 4) * 4;            // row quad for C/D layout
    int node = n0w + col;

    float4 wv0 = *(const float4*)(wxn + node * 8);
    float4 wv1 = *(const float4*)(wxn + node * 8 + 4);

    f32x4 acc[8];
    #pragma unroll
    for (int mt = 0; mt < 8; ++mt) acc[mt] = (f32x4){0.f, 0.f, 0.f, 0.f};

    int xr = (col & 7) << 3;
    const float* W1r0 = W1;
    const float* W1r1 = W1 + F1;

    #pragma unroll
    for (int h = 0; h < 4; ++h) {
        float wa = (h == 0) ? wv0.x : (h == 1) ? wv0.z : (h == 2) ? wv1.x : wv1.z;
        float wb = (h == 0) ? wv0.y : (h == 1) ? wv0.w : (h == 2) ? wv1.y : wv1.w;
        #pragma unroll
        for (int kq = 0; kq < 4; ++kq) {
            int kc = h * 4 + kq;
            int k0 = kc * 32 + krow;
            float4 a0 = *(const float4*)(W1r0 + k0);
            float4 a1 = *(const float4*)(W1r0 + k0 + 4);
            float4 c0 = *(const float4*)(W1r1 + k0);
            float4 c1 = *(const float4*)(W1r1 + k0 + 4);
            float4 b0 = *(const float4*)(b1 + k0);
            float4 b1v = *(const float4*)(b1 + k0 + 4);
            f16x8 bf;
            float v;
            v = wa*a0.x + wb*c0.x + b0.x;  bf[0] = (_Float16)(v > 0.f ? v : 0.f);
            v = wa*a0.y + wb*c0.y + b0.y;  bf[1] = (_Float16)(v > 0.f ? v : 0.f);
            v = wa*a0.z + wb*c0.z + b0.z;  bf[2] = (_Float16)(v > 0.f ? v : 0.f);
            v = wa*a0.w + wb*c0.w + b0.w;  bf[3] = (_Float16)(v > 0.f ? v : 0.f);
            v = wa*a1.x + wb*c1.x + b1v.x; bf[4] = (_Float16)(v > 0.f ? v : 0.f);
            v = wa*a1.y + wb*c1.y + b1v.y; bf[5] = (_Float16)(v > 0.f ? v : 0.f);
            v = wa*a1.z + wb*c1.z + b1v.z; bf[6] = (_Float16)(v > 0.f ? v : 0.f);
            v = wa*a1.w + wb*c1.w + b1v.w; bf[7] = (_Float16)(v > 0.f ? v : 0.f);
            int kbase = col * F1 + (k0 ^ xr);
            #pragma unroll
            for (int mt = 0; mt < 8; ++mt) {
                f16x8 af = *(const f16x8*)(&w2t[mt * 16 * F1 + kbase]);
                acc[mt] = __builtin_amdgcn_mfma_f32_16x16x32_f16(af, bf, acc[mt], 0, 0, 0);
            }
        }
    }

    // ---- epilogue: h2 (fp16) store + attn2 score dots from fp32 accs ----
    float ps = 0.f, pd = 0.f;
    __half* hbase = h2h + (size_t)node * C + qr4;
    #pragma unroll
    for (int mt = 0; mt < 8; ++mt) {
        f32x4 a = acc[mt];
        __half2 lo = __floats2half2_rn(a[0], a[1]);
        __half2 hi = __floats2half2_rn(a[2], a[3]);
        uint2 u; u.x = *(uint*)&lo; u.y = *(uint*)&hi;
        *(uint2*)(hbase + mt * 16) = u;
        float4 av = *(const float4*)(asw + mt * 16 + qr4);
        float4 dv = *(const float4*)(adw + mt * 16 + qr4);
        ps += a[0]*av.x + a[1]*av.y + a[2]*av.z + a[3]*av.w;
        pd += a[0]*dv.x + a[1]*dv.y + a[2]*dv.z + a[3]*dv.w;
    }
    ps += __shfl_xor(ps, 16); ps += __shfl_xor(ps, 32);
    pd += __shfl_xor(pd, 16); pd += __shfl_xor(pd, 32);
    if (lane < 16) { as2[n0w + lane] = ps; ad2[n0w + lane] = pd; }
}

// ---------- layer-2: softmax (no max) + aggregation + bias/relu + projection ----------
// one wave per node; two 32-lane halves each handle alternate edges, 4 ch/lane (8B loads)
__global__ __launch_bounds__(256) void k_agg2(
    const int* __restrict__ offs, const int* __restrict__ scsr,
    const float* __restrict__ as2, const float* __restrict__ ad2,
    const __half* __restrict__ h2h, const float* __restrict__ b2,
    const float* __restrict__ Wp, const float* __restrict__ bp,
    float* __restrict__ out)
{
    int n = blockIdx.x * 4 + (threadIdx.x >> 6);
    int lane = threadIdx.x & 63;
    int half = lane >> 5;                 // 0/1 -> alternate edges
    int cl = lane & 31;                   // channels 4cl..4cl+3
    int beg = offs[n], end = offs[n + 1];
    float adn = ad2[n];
    float a0 = 0.f, a1 = 0.f, a2 = 0.f, a3 = 0.f, psum = 0.f;
    int i = beg + half;
    for (; i + 6 < end; i += 8) {         // 4 edges per half per iter (stride 2)
        int s0 = scsr[i], s1 = scsr[i+2], s2 = scsr[i+4], s3 = scsr[i+6];
        float e0 = as2[s0] + adn, e1 = as2[s1] + adn;
        float e2 = as2[s2] + adn, e3 = as2[s3] + adn;
        uint2 q0 = *(const uint2*)(h2h + (size_t)s0*C + 4*cl);
        uint2 q1 = *(const uint2*)(h2h + (size_t)s1*C + 4*cl);
        uint2 q2 = *(const uint2*)(h2h + (size_t)s2*C + 4*cl);
        uint2 q3 = *(const uint2*)(h2h + (size_t)s3*C + 4*cl);
        e0 = e0 > 0.f ? e0 : 0.2f*e0;  float p0 = __expf(e0);
        e1 = e1 > 0.f ? e1 : 0.2f*e1;  float p1 = __expf(e1);
        e2 = e2 > 0.f ? e2 : 0.2f*e2;  float p2 = __expf(e2);
        e3 = e3 > 0.f ? e3 : 0.2f*e3;  float p3 = __expf(e3);
        psum += (p0 + p1) + (p2 + p3);
        float2 f0a = __half22float2(*(__half2*)&q0.x), f0b = __half22float2(*(__half2*)&q0.y);
        float2 f1a = __half22float2(*(__half2*)&q1.x), f1b = __half22float2(*(__half2*)&q1.y);
        float2 f2a = __half22float2(*(__half2*)&q2.x), f2b = __half22float2(*(__half2*)&q2.y);
        float2 f3a = __half22float2(*(__half2*)&q3.x), f3b = __half22float2(*(__half2*)&q3.y);
        a0 += p0*f0a.x + p1*f1a.x + p2*f2a.x + p3*f3a.x;
        a1 += p0*f0a.y + p1*f1a.y + p2*f2a.y + p3*f3a.y;
        a2 += p0*f0b.x + p1*f1b.x + p2*f2b.x + p3*f3b.x;
        a3 += p0*f0b.y + p1*f1b.y + p2*f2b.y + p3*f3b.y;
    }
    for (; i < end; i += 2) {
        int s = scsr[i];
        float e = as2[s] + adn; e = e > 0.f ? e : 0.2f*e;
        float p = __expf(e);
        psum += p;
        uint2 q = *(const uint2*)(h2h + (size_t)s*C + 4*cl);
        float2 fa = __half22float2(*(__half2*)&q.x), fb = __half22float2(*(__half2*)&q.y);
        a0 += p*fa.x; a1 += p*fa.y; a2 += p*fb.x; a3 += p*fb.y;
    }
    // merge the two halves
    a0 += __shfl_xor(a0, 32); a1 += __shfl_xor(a1, 32);
    a2 += __shfl_xor(a2, 32); a3 += __shfl_xor(a3, 32);
    psum += __shfl_xor(psum, 32);
    float inv = 1.f / (psum + 1e-16f);
    float4 bb = *(const float4*)(b2 + 4*cl);
    float4 wp = *(const float4*)(Wp + 4*cl);
    float v0 = a0*inv + bb.x; v0 = v0 > 0.f ? v0 : 0.f;
    float v1 = a1*inv + bb.y; v1 = v1 > 0.f ? v1 : 0.f;
    float v2 = a2*inv + bb.z; v2 = v2 > 0.f ? v2 : 0.f;
    float v3 = a3*inv + bb.w; v3 = v3 > 0.f ? v3 : 0.f;
    float contrib = v0*wp.x + v1*wp.y + v2*wp.z + v3*wp.w;
    #pragma unroll
    for (int o = 1; o < 32; o <<= 1) contrib += __shfl_xor(contrib, o);
    if (lane == 0) out[n] = contrib + bp[0];
}

// ---------------- host launcher ----------------
extern "C" void kernel_launch(void* const* d_in, const int* in_sizes, int n_in,
                              void* d_out, int out_size, void* d_ws, size_t ws_size,
                              hipStream_t stream)
{
    const float* x    = (const float*)d_in[0];
    const int*   ei   = (const int*)d_in[1];
    const int*   srci = ei;
    const int*   dsti = ei + E_IN;
    const float* W1   = (const float*)d_in[2];
    const float* as1w = (const float*)d_in[3];
    const float* ad1w = (const float*)d_in[4];
    const float* b1   = (const float*)d_in[5];
    const float* W2   = (const float*)d_in[6];
    const float* as2w = (const float*)d_in[7];
    const float* ad2w = (const float*)d_in[8];
    const float* b2   = (const float*)d_in[9];
    const float* Wp   = (const float*)d_in[10];
    const float* bp   = (const float*)d_in[11];
    float* out = (float*)d_out;

    char* ws = (char*)d_ws;
    size_t off = 0;
    auto alloc = [&](size_t bytes) -> char* {
        char* p = ws + off;
        off = (off + bytes + 255) & ~(size_t)255;
        return p;
    };
    float4*    as1v   = (float4*)alloc((size_t)N_NODES * 16);
    float4*    ad1v   = (float4*)alloc((size_t)N_NODES * 16);
    float*     wxn    = (float*)alloc((size_t)N_NODES * 8 * 4);
    __half*    h2h    = (__half*)alloc((size_t)N_NODES * C * 2);
    _Float16*  w2h    = (_Float16*)alloc((size_t)F1 * C * 2);
    float*     as2    = (float*)alloc((size_t)N_NODES * 4);
    float*     ad2    = (float*)alloc((size_t)N_NODES * 4);
    int*       deg    = (int*)alloc((size_t)N_NODES * 4);
    int*       offs   = (int*)alloc((size_t)(N_NODES + 1) * 4);
    int*       cursor = (int*)alloc((size_t)N_NODES * 4);
    int*       scsr   = (int*)alloc((size_t)E_TOT * 4);

    const int EB = 256;
    const int egrid = (E_TOT + EB - 1) / EB;
    const int ngrid = (N_NODES + 255) / 256;

    k_as1z<<<ngrid, 256, 0, stream>>>(x, W1, as1w, ad1w, as1v, ad1v, deg);
    k_w2cvt<<<64, 256, 0, stream>>>(W2, w2h);
    k_hist<<<egrid, EB, 0, stream>>>(dsti, deg);
    k_scan<<<1, 256, 0, stream>>>(deg, offs, cursor);
    k_scatter<<<egrid, EB, 0, stream>>>(srci, dsti, cursor, scsr);
    k_fused1<<<N_NODES / 16, 256, 0, stream>>>(offs, scsr, as1v, ad1v,
                                               (const float2*)x, wxn);
    k_gemm2<<<(N_NODES/16 + 3) / 4, 256, 0, stream>>>(wxn, W1, b1, w2h, as2w, ad2w,
                                                      h2h, as2, ad2);
    k_agg2<<<N_NODES / 4, 256, 0, stream>>>(offs, scsr, as2, ad2, h2h, b2, Wp, bp, out);
}